// Round 9
// baseline (458.023 us; speedup 1.0000x reference)
//
#include <hip/hip_runtime.h>
#include <math.h>

#define HEADS 4
#define HID 32
#define FEAT 128   // HEADS*HID == IN == hidden width everywhere
#define WCOLS 144  // 128 feature cols + 4 ssrc + 4 sdst + 8 zero-pad = 9 MFMA tiles
#define SLOPE 0.2f
#define WHALF (16 * WCOLS * 8)        // fp16 elements per hi (or lo) W image
#define WH8   (WHALF / 8)             // 2304 half8 per image

typedef __attribute__((ext_vector_type(4))) float frag_cd;  // 4 fp32
typedef __attribute__((ext_vector_type(8))) _Float16 half8; // 16B of fp16
typedef __attribute__((ext_vector_type(2))) _Float16 half2v; // 4B of fp16

// ---------------------------------------------------------------------------
// CSR build. hist's atomicAdd return value IS the edge's rank within its
// destination bucket -> scatter needs no atomic. Self-loops folded into
// edge_agg (no CSR slot). ssorted stores src*256 (byte offset into fp16 xw
// row array) so edge_agg needs no per-edge address multiply.
// ---------------------------------------------------------------------------

__global__ void hist_kernel(const int* __restrict__ edge_index, int* __restrict__ deg,
                            int* __restrict__ rank, int E) {
    int e = blockIdx.x * 256 + threadIdx.x;
    if (e < E) rank[e] = atomicAdd(&deg[edge_index[E + e]], 1);
}

#define SCAN_BLK 1024
#define SCAN_CHUNK 4
#define SCAN_TILE (SCAN_BLK * SCAN_CHUNK)

__global__ __launch_bounds__(SCAN_BLK) void scan_partial(const int* __restrict__ deg,
                                                         int* __restrict__ bsum, int Nn) {
    __shared__ int red[SCAN_BLK];
    int t = threadIdx.x;
    int base = blockIdx.x * SCAN_TILE + t * SCAN_CHUNK;
    int s = 0;
#pragma unroll
    for (int i = 0; i < SCAN_CHUNK; i++) {
        int idx = base + i;
        if (idx < Nn) s += deg[idx];
    }
    red[t] = s;
    __syncthreads();
    for (int off = SCAN_BLK / 2; off >= 1; off >>= 1) {
        if (t < off) red[t] += red[t + off];
        __syncthreads();
    }
    if (t == 0) bsum[blockIdx.x] = red[0];
}

__global__ __launch_bounds__(64) void scan_bsum(int* __restrict__ bsum, int nb) {
    int t = threadIdx.x;
    int v = (t < nb) ? bsum[t] : 0;
    int orig = v;
#pragma unroll
    for (int off = 1; off < 64; off <<= 1) {
        int u = __shfl_up(v, off);
        if (t >= off) v += u;
    }
    if (t < nb) bsum[t] = v - orig;
}

__global__ __launch_bounds__(SCAN_BLK) void scan_final(const int* __restrict__ deg,
                                                       const int* __restrict__ bsum,
                                                       int* __restrict__ rowptr, int Nn) {
    __shared__ int sums[SCAN_BLK];
    int t = threadIdx.x;
    int base = blockIdx.x * SCAN_TILE + t * SCAN_CHUNK;
    int loc[SCAN_CHUNK];
    int s = 0;
#pragma unroll
    for (int i = 0; i < SCAN_CHUNK; i++) {
        int idx = base + i;
        int d = (idx < Nn) ? deg[idx] : 0;
        loc[i] = s;
        s += d;
    }
    sums[t] = s;
    __syncthreads();
    for (int off = 1; off < SCAN_BLK; off <<= 1) {
        int v = (t >= off) ? sums[t - off] : 0;
        __syncthreads();
        sums[t] += v;
        __syncthreads();
    }
    int texcl = (t == 0) ? 0 : sums[t - 1];
    int offn = bsum[blockIdx.x] + texcl;
#pragma unroll
    for (int i = 0; i < SCAN_CHUNK; i++) {
        int idx = base + i;
        if (idx < Nn) rowptr[idx] = offn + loc[i];
    }
    if (blockIdx.x == gridDim.x - 1 && t == SCAN_BLK - 1)
        rowptr[Nn] = offn + s;
}

// No atomic: position = rowptr[dst] + precomputed rank. Bijective per bucket.
// Stores src*256 = byte offset of the fp16 feature row.
__global__ void scatter_kernel(const int* __restrict__ edge_index,
                               const int* __restrict__ rank,
                               const int* __restrict__ rowptr,
                               int* __restrict__ ssorted, int E) {
    int e = blockIdx.x * 256 + threadIdx.x;
    if (e < E) {
        int d = edge_index[E + e];
        ssorted[rowptr[d] + rank[e]] = edge_index[e] << 8;
    }
}

// ---------------------------------------------------------------------------
// W prep, all 3 layers: AUGMENTED weight matrix, 144 columns:
//   c in [0,128)   : W[k][c]
//   c in [128,132) : Ws[k][h]  = sum_j W[k][h*32+j] * a_s[h][j]   (h = c-128)
//   c in [132,136) : Wd[k][h]  = sum_j W[k][h*32+j] * a_d[h][j]   (h = c-132)
//   c in [136,144) : 0 (pad to a full 9th MFMA tile)
// fp32 -> fp16 hi/lo split (hi = RNE fp16, lo = residual). hi and lo images
// CONTIGUOUS in one buffer per layer (hi at 0, lo at +WHALF) so the GEMM's
// LDS staging is a single linear copy.
// Layout: wt[L*2*WHALF + (g*WCOLS + c)*8 + j] = hi; +WHALF = lo.
// ---------------------------------------------------------------------------
__global__ void prep_w3(const float* __restrict__ W1, const float* __restrict__ W2,
                        const float* __restrict__ W3,
                        const float* __restrict__ as1, const float* __restrict__ ad1,
                        const float* __restrict__ as2, const float* __restrict__ ad2,
                        const float* __restrict__ as3, const float* __restrict__ ad3,
                        _Float16* __restrict__ wt) {
    int idx = blockIdx.x * 256 + threadIdx.x;
    if (idx >= 3 * FEAT * WCOLS) return;
    int L = idx / (FEAT * WCOLS);
    int rr = idx - L * FEAT * WCOLS;
    int k = rr & 127, c = rr >> 7;           // k in [0,128), c in [0,144)
    const float* W  = (L == 0) ? W1  : (L == 1) ? W2  : W3;
    const float* As = (L == 0) ? as1 : (L == 1) ? as2 : as3;
    const float* Ad = (L == 0) ? ad1 : (L == 1) ? ad2 : ad3;
    float v;
    if (c < 128) {
        v = W[(size_t)k * FEAT + c];
    } else if (c < 136) {
        int s = c - 128;
        int h = s & 3;
        const float* av = (s < 4) ? (As + h * HID) : (Ad + h * HID);
        float acc = 0.f;
        for (int j = 0; j < HID; j++) acc += W[(size_t)k * FEAT + h * HID + j] * av[j];
        v = acc;
    } else {
        v = 0.f;
    }
    _Float16 hi = (_Float16)v;
    _Float16 lo = (_Float16)(v - (float)hi);
    int g = k >> 3, j = k & 7;
    size_t o = (size_t)L * 2 * WHALF + ((size_t)g * WCOLS + c) * 8 + j;
    wt[o] = hi;
    wt[o + WHALF] = lo;
}

// ---------------------------------------------------------------------------
// GEMM via native fp16 MFMA 16x16x32, augmented hi/lo W staged in LDS via
// global_load_lds (one linear 72KB copy). 512-thread blocks (8 waves,
// 256 rows): 72KB LDS -> 2 blocks/CU = 16 waves/CU. Per-wave shape: 2
// row-tiles, B fragment read once per ct, applied to both. A for all 4
// k-steps prefetched BEFORE the staging barrier. (R8 form -- current best.)
// Epilogue: fp16 xw store + direct ssrc/sdst store (no shuffles).
// ---------------------------------------------------------------------------
template <int A16>
__global__ __launch_bounds__(512) void gemm_mfma(const float* __restrict__ Af,
                                                 const _Float16* __restrict__ Ah,
                                                 const _Float16* __restrict__ wt,
                                                 _Float16* __restrict__ xw,
                                                 float* __restrict__ ssrc,
                                                 float* __restrict__ sdst,
                                                 int nrows) {
    __shared__ _Float16 sW[2 * WHALF];   // 72 KB: hi image then lo image
    int tid = threadIdx.x;
    int wave = tid >> 6, lane = tid & 63;

    // linear staging: 2*WH8 = 4608 half8, 8 waves x 9 iters x 64 lanes
    {
        const half8* g8 = (const half8*)wt;
        half8* s8 = (half8*)sW;
#pragma unroll
        for (int it = 0; it < 9; it++) {
            int base = it * 512 + wave * 64;       // half8 index, wave-uniform
            __builtin_amdgcn_global_load_lds(
                (const __attribute__((address_space(1))) void*)(g8 + base + lane),
                (__attribute__((address_space(3))) void*)(s8 + base), 16, 0, 0);
        }
    }

    int r = lane & 15;     // A-row (load) / D-col (store) index within tile
    int q = lane >> 4;     // k-quad (A/B) / row-quad (D)
    int rowbase = blockIdx.x * 256 + wave * 32;

    int arow0 = rowbase + r;      if (arow0 >= nrows) arow0 = nrows - 1;
    int arow1 = rowbase + 16 + r; if (arow1 >= nrows) arow1 = nrows - 1;

    // A prefetch for all 4 k-steps, issued while the LDS DMA drains
    half8 aP0[4], aP1[4];
    if (A16) {
#pragma unroll
        for (int s = 0; s < 4; s++) {
            int kk = s * 32 + q * 8;
            aP0[s] = *(const half8*)(Ah + (size_t)arow0 * FEAT + kk);
            aP1[s] = *(const half8*)(Ah + (size_t)arow1 * FEAT + kk);
        }
    } else {
#pragma unroll
        for (int s = 0; s < 4; s++) {
            int kk = s * 32 + q * 8;
            const float* p0 = Af + (size_t)arow0 * FEAT + kk;
            const float* p1 = Af + (size_t)arow1 * FEAT + kk;
            float4 x0 = *(const float4*)p0;
            float4 x1 = *(const float4*)(p0 + 4);
            float4 y0 = *(const float4*)p1;
            float4 y1 = *(const float4*)(p1 + 4);
            aP0[s][0] = (_Float16)x0.x; aP0[s][1] = (_Float16)x0.y;
            aP0[s][2] = (_Float16)x0.z; aP0[s][3] = (_Float16)x0.w;
            aP0[s][4] = (_Float16)x1.x; aP0[s][5] = (_Float16)x1.y;
            aP0[s][6] = (_Float16)x1.z; aP0[s][7] = (_Float16)x1.w;
            aP1[s][0] = (_Float16)y0.x; aP1[s][1] = (_Float16)y0.y;
            aP1[s][2] = (_Float16)y0.z; aP1[s][3] = (_Float16)y0.w;
            aP1[s][4] = (_Float16)y1.x; aP1[s][5] = (_Float16)y1.y;
            aP1[s][6] = (_Float16)y1.z; aP1[s][7] = (_Float16)y1.w;
        }
    }
    __syncthreads();

    frag_cd acc0[9], acc1[9];
#pragma unroll
    for (int ct = 0; ct < 9; ct++) {
        acc0[ct] = (frag_cd){0.f, 0.f, 0.f, 0.f};
        acc1[ct] = (frag_cd){0.f, 0.f, 0.f, 0.f};
    }

    const half8* sB = (const half8*)sW;
#pragma unroll
    for (int s = 0; s < 4; s++) {
        int g = s * 4 + q;
        const half8* bh = sB + (size_t)g * WCOLS;
        const half8* bl = sB + WH8 + (size_t)g * WCOLS;
        half8 a0v = aP0[s], a1v = aP1[s];
#pragma unroll
        for (int ct = 0; ct < 9; ct++) {
            int c = ct * 16 + r;
            half8 vh = bh[c];
            half8 vl = bl[c];
            acc0[ct] = __builtin_amdgcn_mfma_f32_16x16x32_f16(a0v, vh, acc0[ct], 0, 0, 0);
            acc0[ct] = __builtin_amdgcn_mfma_f32_16x16x32_f16(a0v, vl, acc0[ct], 0, 0, 0);
            acc1[ct] = __builtin_amdgcn_mfma_f32_16x16x32_f16(a1v, vh, acc1[ct], 0, 0, 0);
            acc1[ct] = __builtin_amdgcn_mfma_f32_16x16x32_f16(a1v, vl, acc1[ct], 0, 0, 0);
        }
    }

    // D layout: col = ct*16 + r, row = q*4 + gi  [m89-verified]
#pragma unroll
    for (int gi = 0; gi < 4; gi++) {
        int rr0 = rowbase + q * 4 + gi;
        if (rr0 < nrows) {
#pragma unroll
            for (int ct = 0; ct < 8; ct++)
                xw[(size_t)rr0 * FEAT + ct * 16 + r] = (_Float16)acc0[ct][gi];
            if (r < 4)      ssrc[rr0 * HEADS + r] = acc0[8][gi];
            else if (r < 8) sdst[rr0 * HEADS + (r - 4)] = acc0[8][gi];
        }
        int rr1 = rowbase + 16 + q * 4 + gi;
        if (rr1 < nrows) {
#pragma unroll
            for (int ct = 0; ct < 8; ct++)
                xw[(size_t)rr1 * FEAT + ct * 16 + r] = (_Float16)acc1[ct][gi];
            if (r < 4)      ssrc[rr1 * HEADS + r] = acc1[8][gi];
            else if (r < 8) sdst[rr1 * HEADS + (r - 4)] = acc1[8][gi];
        }
    }
}

// ---------------------------------------------------------------------------
// Single-pass edge softmax+aggregate, one wave per node, 4 edge slots.
// lane = slot(=lane/16) x q(=lane%16, channel octet 8q..8q+7).
// Per edge: 16 lanes x 16 B (fp16) = full 256 B row. 4-DEEP ring pipeline
// (unrolled, static stage indices -> no rotation movs, stays in VGPRs):
// 16 random gathers in flight per wave (was 8) -- the kernel is MLP-bound,
// not pin-BW-bound (R1 512B rows: 3.9 TB/s; R8 256B rows: 2.6 TB/s at same
// FETCH). Consumption order per slot unchanged (i, i+4, ...) -> bit-exact.
// Self-loop in slot 0 prologue. Epilogue: slot-spread ELU/bias/store.
// ---------------------------------------------------------------------------
__global__ __launch_bounds__(256) void edge_agg(const _Float16* __restrict__ xw,
                                                const float* __restrict__ ssrc,
                                                const float* __restrict__ sdst,
                                                const int* __restrict__ rowptr,
                                                const int* __restrict__ ssorted,
                                                const float* __restrict__ bias,
                                                float* __restrict__ out,
                                                _Float16* __restrict__ outh,
                                                int final_layer, int Nn) {
    int wid = blockIdx.x * 4 + (threadIdx.x >> 6);   // node index
    if (wid >= Nn) return;
    int lane = threadIdx.x & 63;
    int slot = lane >> 4;       // edge slot 0..3
    int q = lane & 15;          // channel octet (channels 8q..8q+7)
    int qh = q >> 2;            // head of this octet

    const char* xwb = (const char*)xw;
    const char* scb = (const char*)ssrc;
    int xoff = q << 4;          // lane byte offset within row
    int soff = qh << 2;

    int beg = rowptr[wid], end = rowptr[wid + 1];
    float sdh = sdst[wid * HEADS + qh];

    float4 a0 = make_float4(0.f, 0.f, 0.f, 0.f);
    float4 a1 = make_float4(0.f, 0.f, 0.f, 0.f);
    float den = 0.f;

    // self-loop (PyG adds one per node): slot 0 handles it
    if (slot == 0) {
        int off = wid << 8;
        float v = *(const float*)(scb + (off >> 4) + soff) + sdh;
        v = v > 0.f ? v : SLOPE * v;
        float w = __expf(v);
        den = w;
        const half8 hv = *(const half8*)(xwb + (size_t)(unsigned)off + xoff);
        a0.x = w * (float)hv[0]; a0.y = w * (float)hv[1];
        a0.z = w * (float)hv[2]; a0.w = w * (float)hv[3];
        a1.x = w * (float)hv[4]; a1.y = w * (float)hv[5];
        a1.z = w * (float)hv[6]; a1.w = w * (float)hv[7];
    }

    // 4-deep ring pipeline. Stage k holds edge index cs + 4k relative order;
    // prologue fills all 4 stages, steady state consumes stage k and reloads
    // it with the edge 16 positions ahead.
    float scS[4];
    half8 hvS[4];
    int ld = beg + slot;
#pragma unroll
    for (int k = 0; k < 4; k++) {
        scS[k] = 0.f;
        hvS[k] = (half8)(_Float16)0.f;
        if (ld < end) {
            int off = ssorted[ld];
            scS[k] = *(const float*)(scb + (off >> 4) + soff);
            hvS[k] = *(const half8*)(xwb + (size_t)(unsigned)off + xoff);
        }
        ld += 4;
    }
    int cs = beg + slot;
    while (cs < end) {
#pragma unroll
        for (int k = 0; k < 4; k++) {
            if (cs < end) {
                // consume stage k (loaded 4 ring-steps ago)
                float v = scS[k] + sdh;
                v = v > 0.f ? v : SLOPE * v;
                float w = __expf(v);              // safe: |v| ~ O(6)
                den += w;
                half8 hv = hvS[k];
                // reload stage k with the edge 16 ahead
                if (ld < end) {
                    int off = ssorted[ld];
                    scS[k] = *(const float*)(scb + (off >> 4) + soff);
                    hvS[k] = *(const half8*)(xwb + (size_t)(unsigned)off + xoff);
                }
                a0.x += w * (float)hv[0]; a0.y += w * (float)hv[1];
                a0.z += w * (float)hv[2]; a0.w += w * (float)hv[3];
                a1.x += w * (float)hv[4]; a1.y += w * (float)hv[5];
                a1.z += w * (float)hv[6]; a1.w += w * (float)hv[7];
            }
            cs += 4;
            ld += 4;
        }
    }

    // fold the 4 edge slots (lane bits 4,5)
#pragma unroll
    for (int m = 16; m <= 32; m <<= 1) {
        a0.x += __shfl_xor(a0.x, m); a0.y += __shfl_xor(a0.y, m);
        a0.z += __shfl_xor(a0.z, m); a0.w += __shfl_xor(a0.w, m);
        a1.x += __shfl_xor(a1.x, m); a1.y += __shfl_xor(a1.y, m);
        a1.z += __shfl_xor(a1.z, m); a1.w += __shfl_xor(a1.w, m);
        den  += __shfl_xor(den, m);
    }

    float inv = 1.f / den;                        // den>0 (self loop); per-head
    a0.x *= inv; a0.y *= inv; a0.z *= inv; a0.w *= inv;
    a1.x *= inv; a1.y *= inv; a1.z *= inv; a1.w *= inv;

    if (!final_layer) {
        // slot-spread epilogue: every slot holds identical folded values;
        // slot s handles channels 8q+2s, 8q+2s+1. All 64 lanes active.
        float v0, v1;
        if (slot == 0)      { v0 = a0.x; v1 = a0.y; }
        else if (slot == 1) { v0 = a0.z; v1 = a0.w; }
        else if (slot == 2) { v0 = a1.x; v1 = a1.y; }
        else                { v0 = a1.z; v1 = a1.w; }
        const float2 bb = *(const float2*)(bias + q * 8 + slot * 2);
        v0 += bb.x; v1 += bb.y;
        // ELU: exp(x)-1 == expm1(x) to ~2^-22 abs here (x<=0, fp32 exp)
        v0 = v0 > 0.f ? v0 : __expf(v0) - 1.f;
        v1 = v1 > 0.f ? v1 : __expf(v1) - 1.f;
        half2v hv2;
        hv2[0] = (_Float16)v0; hv2[1] = (_Float16)v1;
        *(half2v*)(outh + (size_t)wid * FEAT + q * 8 + slot * 2) = hv2;
    } else {
        // head-mean: same within-head channels sit at lanes q, q^4, q^8 (bits 2,3)
#pragma unroll
        for (int m = 4; m <= 8; m <<= 1) {
            a0.x += __shfl_xor(a0.x, m); a0.y += __shfl_xor(a0.y, m);
            a0.z += __shfl_xor(a0.z, m); a0.w += __shfl_xor(a0.w, m);
            a1.x += __shfl_xor(a1.x, m); a1.y += __shfl_xor(a1.y, m);
            a1.z += __shfl_xor(a1.z, m); a1.w += __shfl_xor(a1.w, m);
        }
        if (q < 4) {
            // lanes q<4 hold head-sums for within-head cols 8q..8q+7;
            // slot s handles cols 8q+2s, 8q+2s+1 (16 lanes x 8B = full row)
            float v0, v1;
            if (slot == 0)      { v0 = a0.x; v1 = a0.y; }
            else if (slot == 1) { v0 = a0.z; v1 = a0.w; }
            else if (slot == 2) { v0 = a1.x; v1 = a1.y; }
            else                { v0 = a1.z; v1 = a1.w; }
            const float2 bb = *(const float2*)(bias + q * 8 + slot * 2);
            float2 rv;
            rv.x = v0 * 0.25f + bb.x;
            rv.y = v1 * 0.25f + bb.y;
            *(float2*)(out + (size_t)wid * HID + q * 8 + slot * 2) = rv;
        }
    }
}

// ---------------------------------------------------------------------------
// Launch
// ---------------------------------------------------------------------------
extern "C" void kernel_launch(void* const* d_in, const int* in_sizes, int n_in,
                              void* d_out, int out_size, void* d_ws, size_t ws_size,
                              hipStream_t stream) {
    const float* x   = (const float*)d_in[0];
    const int* eidx  = (const int*)d_in[1];
    const float* W1  = (const float*)d_in[2];
    const float* as1 = (const float*)d_in[3];
    const float* ad1 = (const float*)d_in[4];
    const float* b1  = (const float*)d_in[5];
    const float* W2  = (const float*)d_in[6];
    const float* as2 = (const float*)d_in[7];
    const float* ad2 = (const float*)d_in[8];
    const float* b2  = (const float*)d_in[9];
    const float* W3  = (const float*)d_in[10];
    const float* as3 = (const float*)d_in[11];
    const float* ad3 = (const float*)d_in[12];
    const float* b3  = (const float*)d_in[13];

    const int Nn = in_sizes[0] / FEAT;   // 100000
    const int E  = in_sizes[1] / 2;      // 1200000

    char* w = (char*)d_ws;
    size_t off = 0;
    auto alloc = [&](size_t bytes) {
        void* p = w + off;
        off += (bytes + 255) & ~(size_t)255;
        return p;
    };
    _Float16* bufB = (_Float16*)alloc((size_t)Nn * FEAT * 2); // inter-layer fp16
    _Float16* xwh  = (_Float16*)alloc((size_t)Nn * FEAT * 2); // post-GEMM features (fp16)
    float* ssrc   = (float*)alloc((size_t)Nn * HEADS * 4);
    float* sdst   = (float*)alloc((size_t)Nn * HEADS * 4);
    int*   rowptr = (int*)alloc((size_t)(Nn + 1) * 4);
    int*   deg    = (int*)alloc((size_t)Nn * 4);
    int*   rank   = (int*)alloc((size_t)E * 4);
    int*   ssort  = (int*)alloc((size_t)E * 4);
    int*   bsum   = (int*)alloc(64 * 4);
    _Float16* wt  = (_Float16*)alloc((size_t)3 * 2 * WHALF * 2);
    (void)ws_size;

    // ---- CSR build + all-layer W prep (once)
    hipMemsetAsync(deg, 0, (size_t)Nn * 4, stream);
    hist_kernel<<<(E + 255) / 256, 256, 0, stream>>>(eidx, deg, rank, E);
    prep_w3<<<(3 * FEAT * WCOLS + 255) / 256, 256, 0, stream>>>(
        W1, W2, W3, as1, ad1, as2, ad2, as3, ad3, wt);
    int nscan = (Nn + SCAN_TILE - 1) / SCAN_TILE;
    scan_partial<<<nscan, SCAN_BLK, 0, stream>>>(deg, bsum, Nn);
    scan_bsum<<<1, 64, 0, stream>>>(bsum, nscan);
    scan_final<<<nscan, SCAN_BLK, 0, stream>>>(deg, bsum, rowptr, Nn);
    scatter_kernel<<<(E + 255) / 256, 256, 0, stream>>>(eidx, rank, rowptr, ssort, E);

    const int gemm_grid = (Nn + 255) / 256;
    const int agg_grid  = (Nn + 3) / 4;

    const float* bs[3] = {b1, b2, b3};

    for (int L = 0; L < 3; L++) {
        const size_t woff = (size_t)L * 2 * WHALF;
        if (L == 0) {
            gemm_mfma<0><<<gemm_grid, 512, 0, stream>>>(x, (const _Float16*)nullptr,
                                                        wt + woff,
                                                        xwh, ssrc, sdst, Nn);
        } else {
            gemm_mfma<1><<<gemm_grid, 512, 0, stream>>>((const float*)nullptr, bufB,
                                                        wt + woff,
                                                        xwh, ssrc, sdst, Nn);
        }
        edge_agg<<<agg_grid, 256, 0, stream>>>(xwh, ssrc, sdst, rowptr, ssort,
                                               bs[L], (L == 2) ? (float*)d_out : nullptr,
                                               bufB, L == 2, Nn);
    }
}

// Round 10
// 433.562 us; speedup vs baseline: 1.0564x; 1.0564x over previous
//
#include <hip/hip_runtime.h>
#include <math.h>

#define HEADS 4
#define HID 32
#define FEAT 128   // HEADS*HID == IN == hidden width everywhere
#define WCOLS 144  // 128 feature cols + 4 ssrc + 4 sdst + 8 zero-pad = 9 MFMA tiles
#define SLOPE 0.2f
#define WHALF (16 * WCOLS * 8)        // fp16 elements per hi (or lo) W image
#define WH8   (WHALF / 8)             // 2304 half8 per image

typedef __attribute__((ext_vector_type(4))) float frag_cd;  // 4 fp32
typedef __attribute__((ext_vector_type(8))) _Float16 half8; // 16B of fp16
typedef __attribute__((ext_vector_type(2))) _Float16 half2v; // 4B of fp16

// ---------------------------------------------------------------------------
// CSR build. hist's atomicAdd return value IS the edge's rank within its
// destination bucket -> scatter needs no atomic. Self-loops folded into
// edge_agg (no CSR slot). ssorted stores src*256 (byte offset into fp16 xw
// row array). prep_w3 is FUSED into the hist launch (role-split by blockIdx:
// independent work, one launch). The scatter is FUSED into the layer-0 GEMM
// launch (blocks >= gemm_blocks): scatter needs only rowptr/rank, gemm L0
// needs only x/W -- independent, and the gemm grid (391 blocks at 2/CU)
// leaves ~24% of CUs idle, which the scatter blocks fill for free overlap.
// ---------------------------------------------------------------------------

// fused hist (rank capture) + W prep.
// blocks [0, HB): histogram. blocks [HB, HB+PB): augmented-W prep.
__global__ void hist_prep(const int* __restrict__ edge_index, int* __restrict__ deg,
                          int* __restrict__ rank, int E, int HB,
                          const float* __restrict__ W1, const float* __restrict__ W2,
                          const float* __restrict__ W3,
                          const float* __restrict__ as1, const float* __restrict__ ad1,
                          const float* __restrict__ as2, const float* __restrict__ ad2,
                          const float* __restrict__ as3, const float* __restrict__ ad3,
                          _Float16* __restrict__ wt) {
    if ((int)blockIdx.x < HB) {
        int e = blockIdx.x * 256 + threadIdx.x;
        if (e < E) rank[e] = atomicAdd(&deg[edge_index[E + e]], 1);
        return;
    }
    int idx = (blockIdx.x - HB) * 256 + threadIdx.x;
    if (idx >= 3 * FEAT * WCOLS) return;
    int L = idx / (FEAT * WCOLS);
    int rr = idx - L * FEAT * WCOLS;
    int k = rr & 127, c = rr >> 7;           // k in [0,128), c in [0,144)
    const float* W  = (L == 0) ? W1  : (L == 1) ? W2  : W3;
    const float* As = (L == 0) ? as1 : (L == 1) ? as2 : as3;
    const float* Ad = (L == 0) ? ad1 : (L == 1) ? ad2 : ad3;
    float v;
    if (c < 128) {
        v = W[(size_t)k * FEAT + c];
    } else if (c < 136) {
        int s = c - 128;
        int h = s & 3;
        const float* av = (s < 4) ? (As + h * HID) : (Ad + h * HID);
        float acc = 0.f;
        for (int j = 0; j < HID; j++) acc += W[(size_t)k * FEAT + h * HID + j] * av[j];
        v = acc;
    } else {
        v = 0.f;
    }
    _Float16 hi = (_Float16)v;
    _Float16 lo = (_Float16)(v - (float)hi);
    int g = k >> 3, j = k & 7;
    size_t o = (size_t)L * 2 * WHALF + ((size_t)g * WCOLS + c) * 8 + j;
    wt[o] = hi;
    wt[o + WHALF] = lo;
}

#define SCAN_BLK 1024
#define SCAN_CHUNK 4
#define SCAN_TILE (SCAN_BLK * SCAN_CHUNK)

__global__ __launch_bounds__(SCAN_BLK) void scan_partial(const int* __restrict__ deg,
                                                         int* __restrict__ bsum, int Nn) {
    __shared__ int red[SCAN_BLK];
    int t = threadIdx.x;
    int base = blockIdx.x * SCAN_TILE + t * SCAN_CHUNK;
    int s = 0;
#pragma unroll
    for (int i = 0; i < SCAN_CHUNK; i++) {
        int idx = base + i;
        if (idx < Nn) s += deg[idx];
    }
    red[t] = s;
    __syncthreads();
    for (int off = SCAN_BLK / 2; off >= 1; off >>= 1) {
        if (t < off) red[t] += red[t + off];
        __syncthreads();
    }
    if (t == 0) bsum[blockIdx.x] = red[0];
}

__global__ __launch_bounds__(64) void scan_bsum(int* __restrict__ bsum, int nb) {
    int t = threadIdx.x;
    int v = (t < nb) ? bsum[t] : 0;
    int orig = v;
#pragma unroll
    for (int off = 1; off < 64; off <<= 1) {
        int u = __shfl_up(v, off);
        if (t >= off) v += u;
    }
    if (t < nb) bsum[t] = v - orig;
}

__global__ __launch_bounds__(SCAN_BLK) void scan_final(const int* __restrict__ deg,
                                                       const int* __restrict__ bsum,
                                                       int* __restrict__ rowptr, int Nn) {
    __shared__ int sums[SCAN_BLK];
    int t = threadIdx.x;
    int base = blockIdx.x * SCAN_TILE + t * SCAN_CHUNK;
    int loc[SCAN_CHUNK];
    int s = 0;
#pragma unroll
    for (int i = 0; i < SCAN_CHUNK; i++) {
        int idx = base + i;
        int d = (idx < Nn) ? deg[idx] : 0;
        loc[i] = s;
        s += d;
    }
    sums[t] = s;
    __syncthreads();
    for (int off = 1; off < SCAN_BLK; off <<= 1) {
        int v = (t >= off) ? sums[t - off] : 0;
        __syncthreads();
        sums[t] += v;
        __syncthreads();
    }
    int texcl = (t == 0) ? 0 : sums[t - 1];
    int offn = bsum[blockIdx.x] + texcl;
#pragma unroll
    for (int i = 0; i < SCAN_CHUNK; i++) {
        int idx = base + i;
        if (idx < Nn) rowptr[idx] = offn + loc[i];
    }
    if (blockIdx.x == gridDim.x - 1 && t == SCAN_BLK - 1)
        rowptr[Nn] = offn + s;
}

// ---------------------------------------------------------------------------
// GEMM via native fp16 MFMA 16x16x32, augmented hi/lo W staged in LDS via
// global_load_lds (one linear 72KB copy). 512-thread blocks (8 waves,
// 256 rows): 72KB LDS -> 2 blocks/CU = 16 waves/CU. Per-wave shape: 2
// row-tiles, B fragment read once per ct, applied to both. A for all 4
// k-steps prefetched BEFORE the staging barrier. (R8 form -- measured best.)
// Epilogue: fp16 xw store + direct ssrc/sdst store (no shuffles).
// SCAT=1 (layer 0): blocks >= gemm_blocks instead run the no-atomic CSR
// scatter, grid-strided. They fill CUs left idle by the gemm grid.
// ---------------------------------------------------------------------------
template <int A16, int SCAT>
__global__ __launch_bounds__(512) void gemm_mfma(const float* __restrict__ Af,
                                                 const _Float16* __restrict__ Ah,
                                                 const _Float16* __restrict__ wt,
                                                 _Float16* __restrict__ xw,
                                                 float* __restrict__ ssrc,
                                                 float* __restrict__ sdst,
                                                 int nrows, int gemm_blocks,
                                                 const int* __restrict__ eidx,
                                                 const int* __restrict__ rank,
                                                 const int* __restrict__ rowptr,
                                                 int* __restrict__ ssorted, int E) {
    if (SCAT && (int)blockIdx.x >= gemm_blocks) {
        int t = (blockIdx.x - gemm_blocks) * 512 + threadIdx.x;
        int stride = (gridDim.x - gemm_blocks) * 512;
        for (int e = t; e < E; e += stride) {
            int d = eidx[E + e];
            ssorted[rowptr[d] + rank[e]] = eidx[e] << 8;
        }
        return;
    }

    __shared__ _Float16 sW[2 * WHALF];   // 72 KB: hi image then lo image
    int tid = threadIdx.x;
    int wave = tid >> 6, lane = tid & 63;

    // linear staging: 2*WH8 = 4608 half8, 8 waves x 9 iters x 64 lanes
    {
        const half8* g8 = (const half8*)wt;
        half8* s8 = (half8*)sW;
#pragma unroll
        for (int it = 0; it < 9; it++) {
            int base = it * 512 + wave * 64;       // half8 index, wave-uniform
            __builtin_amdgcn_global_load_lds(
                (const __attribute__((address_space(1))) void*)(g8 + base + lane),
                (__attribute__((address_space(3))) void*)(s8 + base), 16, 0, 0);
        }
    }

    int r = lane & 15;     // A-row (load) / D-col (store) index within tile
    int q = lane >> 4;     // k-quad (A/B) / row-quad (D)
    int rowbase = blockIdx.x * 256 + wave * 32;

    int arow0 = rowbase + r;      if (arow0 >= nrows) arow0 = nrows - 1;
    int arow1 = rowbase + 16 + r; if (arow1 >= nrows) arow1 = nrows - 1;

    // A prefetch for all 4 k-steps, issued while the LDS DMA drains
    half8 aP0[4], aP1[4];
    if (A16) {
#pragma unroll
        for (int s = 0; s < 4; s++) {
            int kk = s * 32 + q * 8;
            aP0[s] = *(const half8*)(Ah + (size_t)arow0 * FEAT + kk);
            aP1[s] = *(const half8*)(Ah + (size_t)arow1 * FEAT + kk);
        }
    } else {
#pragma unroll
        for (int s = 0; s < 4; s++) {
            int kk = s * 32 + q * 8;
            const float* p0 = Af + (size_t)arow0 * FEAT + kk;
            const float* p1 = Af + (size_t)arow1 * FEAT + kk;
            float4 x0 = *(const float4*)p0;
            float4 x1 = *(const float4*)(p0 + 4);
            float4 y0 = *(const float4*)p1;
            float4 y1 = *(const float4*)(p1 + 4);
            aP0[s][0] = (_Float16)x0.x; aP0[s][1] = (_Float16)x0.y;
            aP0[s][2] = (_Float16)x0.z; aP0[s][3] = (_Float16)x0.w;
            aP0[s][4] = (_Float16)x1.x; aP0[s][5] = (_Float16)x1.y;
            aP0[s][6] = (_Float16)x1.z; aP0[s][7] = (_Float16)x1.w;
            aP1[s][0] = (_Float16)y0.x; aP1[s][1] = (_Float16)y0.y;
            aP1[s][2] = (_Float16)y0.z; aP1[s][3] = (_Float16)y0.w;
            aP1[s][4] = (_Float16)y1.x; aP1[s][5] = (_Float16)y1.y;
            aP1[s][6] = (_Float16)y1.z; aP1[s][7] = (_Float16)y1.w;
        }
    }
    __syncthreads();

    frag_cd acc0[9], acc1[9];
#pragma unroll
    for (int ct = 0; ct < 9; ct++) {
        acc0[ct] = (frag_cd){0.f, 0.f, 0.f, 0.f};
        acc1[ct] = (frag_cd){0.f, 0.f, 0.f, 0.f};
    }

    const half8* sB = (const half8*)sW;
#pragma unroll
    for (int s = 0; s < 4; s++) {
        int g = s * 4 + q;
        const half8* bh = sB + (size_t)g * WCOLS;
        const half8* bl = sB + WH8 + (size_t)g * WCOLS;
        half8 a0v = aP0[s], a1v = aP1[s];
#pragma unroll
        for (int ct = 0; ct < 9; ct++) {
            int c = ct * 16 + r;
            half8 vh = bh[c];
            half8 vl = bl[c];
            acc0[ct] = __builtin_amdgcn_mfma_f32_16x16x32_f16(a0v, vh, acc0[ct], 0, 0, 0);
            acc0[ct] = __builtin_amdgcn_mfma_f32_16x16x32_f16(a0v, vl, acc0[ct], 0, 0, 0);
            acc1[ct] = __builtin_amdgcn_mfma_f32_16x16x32_f16(a1v, vh, acc1[ct], 0, 0, 0);
            acc1[ct] = __builtin_amdgcn_mfma_f32_16x16x32_f16(a1v, vl, acc1[ct], 0, 0, 0);
        }
    }

    // D layout: col = ct*16 + r, row = q*4 + gi  [m89-verified]
#pragma unroll
    for (int gi = 0; gi < 4; gi++) {
        int rr0 = rowbase + q * 4 + gi;
        if (rr0 < nrows) {
#pragma unroll
            for (int ct = 0; ct < 8; ct++)
                xw[(size_t)rr0 * FEAT + ct * 16 + r] = (_Float16)acc0[ct][gi];
            if (r < 4)      ssrc[rr0 * HEADS + r] = acc0[8][gi];
            else if (r < 8) sdst[rr0 * HEADS + (r - 4)] = acc0[8][gi];
        }
        int rr1 = rowbase + 16 + q * 4 + gi;
        if (rr1 < nrows) {
#pragma unroll
            for (int ct = 0; ct < 8; ct++)
                xw[(size_t)rr1 * FEAT + ct * 16 + r] = (_Float16)acc1[ct][gi];
            if (r < 4)      ssrc[rr1 * HEADS + r] = acc1[8][gi];
            else if (r < 8) sdst[rr1 * HEADS + (r - 4)] = acc1[8][gi];
        }
    }
}

// ---------------------------------------------------------------------------
// Single-pass edge softmax+aggregate, one wave per node, 4 edge slots.
// (R8 form verbatim -- measured best: 2-deep pipeline, 24 VGPR. The R9
// 4-deep ring regressed: mean degree 13 -> ~3 trips/slot, ring overhead
// dominated. Do not deepen.)
// ---------------------------------------------------------------------------
__global__ __launch_bounds__(256) void edge_agg(const _Float16* __restrict__ xw,
                                                const float* __restrict__ ssrc,
                                                const float* __restrict__ sdst,
                                                const int* __restrict__ rowptr,
                                                const int* __restrict__ ssorted,
                                                const float* __restrict__ bias,
                                                float* __restrict__ out,
                                                _Float16* __restrict__ outh,
                                                int final_layer, int Nn) {
    int wid = blockIdx.x * 4 + (threadIdx.x >> 6);   // node index
    if (wid >= Nn) return;
    int lane = threadIdx.x & 63;
    int slot = lane >> 4;       // edge slot 0..3
    int q = lane & 15;          // channel octet (channels 8q..8q+7)
    int qh = q >> 2;            // head of this octet

    const char* xwb = (const char*)xw;
    const char* scb = (const char*)ssrc;
    int xoff = q << 4;          // lane byte offset within row
    int soff = qh << 2;

    int beg = rowptr[wid], end = rowptr[wid + 1];
    float sdh = sdst[wid * HEADS + qh];

    float4 a0 = make_float4(0.f, 0.f, 0.f, 0.f);
    float4 a1 = make_float4(0.f, 0.f, 0.f, 0.f);
    float den = 0.f;

    // self-loop (PyG adds one per node): slot 0 handles it
    if (slot == 0) {
        int off = wid << 8;
        float v = *(const float*)(scb + (off >> 4) + soff) + sdh;
        v = v > 0.f ? v : SLOPE * v;
        float w = __expf(v);
        den = w;
        const half8 hv = *(const half8*)(xwb + (size_t)(unsigned)off + xoff);
        a0.x = w * (float)hv[0]; a0.y = w * (float)hv[1];
        a0.z = w * (float)hv[2]; a0.w = w * (float)hv[3];
        a1.x = w * (float)hv[4]; a1.y = w * (float)hv[5];
        a1.z = w * (float)hv[6]; a1.w = w * (float)hv[7];
    }

    // 2-deep pipelined edge loop
    int iC = beg + slot;
    int iN = iC + 4;
    bool haveC = (iC < end);
    bool haveN = (iN < end);
    float scC = 0.f, scN = 0.f;
    half8 hvC = (half8)(_Float16)0.f, hvN = (half8)(_Float16)0.f;
    if (haveC) {
        int offC = ssorted[iC];
        scC = *(const float*)(scb + (offC >> 4) + soff);
        hvC = *(const half8*)(xwb + (size_t)(unsigned)offC + xoff);
    }
    if (haveN) {
        int offN = ssorted[iN];
        scN = *(const float*)(scb + (offN >> 4) + soff);
        hvN = *(const half8*)(xwb + (size_t)(unsigned)offN + xoff);
    }
    while (haveC) {
        int iNN = iN + 4;
        bool haveNN = (iNN < end);
        int offNN = 0;
        if (haveNN) offNN = ssorted[iNN];         // issue next-next index load
        // consume C's score (loaded 2 iterations ago)
        float v = scC + sdh;
        v = v > 0.f ? v : SLOPE * v;
        float w = __expf(v);                      // safe: |v| ~ O(6)
        den += w;
        // issue NN's loads (dependent only on offNN)
        float scNN = 0.f;
        half8 hvNN = (half8)(_Float16)0.f;
        if (haveNN) {
            scNN = *(const float*)(scb + (offNN >> 4) + soff);
            hvNN = *(const half8*)(xwb + (size_t)(unsigned)offNN + xoff);
        }
        // consume C's gather
        a0.x += w * (float)hvC[0]; a0.y += w * (float)hvC[1];
        a0.z += w * (float)hvC[2]; a0.w += w * (float)hvC[3];
        a1.x += w * (float)hvC[4]; a1.y += w * (float)hvC[5];
        a1.z += w * (float)hvC[6]; a1.w += w * (float)hvC[7];
        // rotate C <- N <- NN
        iN = iNN;
        haveC = haveN; haveN = haveNN;
        scC = scN; scN = scNN;
        hvC = hvN; hvN = hvNN;
    }

    // fold the 4 edge slots (lane bits 4,5)
#pragma unroll
    for (int m = 16; m <= 32; m <<= 1) {
        a0.x += __shfl_xor(a0.x, m); a0.y += __shfl_xor(a0.y, m);
        a0.z += __shfl_xor(a0.z, m); a0.w += __shfl_xor(a0.w, m);
        a1.x += __shfl_xor(a1.x, m); a1.y += __shfl_xor(a1.y, m);
        a1.z += __shfl_xor(a1.z, m); a1.w += __shfl_xor(a1.w, m);
        den  += __shfl_xor(den, m);
    }

    float inv = 1.f / den;                        // den>0 (self loop); per-head
    a0.x *= inv; a0.y *= inv; a0.z *= inv; a0.w *= inv;
    a1.x *= inv; a1.y *= inv; a1.z *= inv; a1.w *= inv;

    if (!final_layer) {
        // slot-spread epilogue: every slot holds identical folded values;
        // slot s handles channels 8q+2s, 8q+2s+1. All 64 lanes active.
        float v0, v1;
        if (slot == 0)      { v0 = a0.x; v1 = a0.y; }
        else if (slot == 1) { v0 = a0.z; v1 = a0.w; }
        else if (slot == 2) { v0 = a1.x; v1 = a1.y; }
        else                { v0 = a1.z; v1 = a1.w; }
        const float2 bb = *(const float2*)(bias + q * 8 + slot * 2);
        v0 += bb.x; v1 += bb.y;
        // ELU: exp(x)-1 == expm1(x) to ~2^-22 abs here (x<=0, fp32 exp)
        v0 = v0 > 0.f ? v0 : __expf(v0) - 1.f;
        v1 = v1 > 0.f ? v1 : __expf(v1) - 1.f;
        half2v hv2;
        hv2[0] = (_Float16)v0; hv2[1] = (_Float16)v1;
        *(half2v*)(outh + (size_t)wid * FEAT + q * 8 + slot * 2) = hv2;
    } else {
        // head-mean: same within-head channels sit at lanes q, q^4, q^8 (bits 2,3)
#pragma unroll
        for (int m = 4; m <= 8; m <<= 1) {
            a0.x += __shfl_xor(a0.x, m); a0.y += __shfl_xor(a0.y, m);
            a0.z += __shfl_xor(a0.z, m); a0.w += __shfl_xor(a0.w, m);
            a1.x += __shfl_xor(a1.x, m); a1.y += __shfl_xor(a1.y, m);
            a1.z += __shfl_xor(a1.z, m); a1.w += __shfl_xor(a1.w, m);
        }
        if (q < 4) {
            // lanes q<4 hold head-sums for within-head cols 8q..8q+7;
            // slot s handles cols 8q+2s, 8q+2s+1 (16 lanes x 8B = full row)
            float v0, v1;
            if (slot == 0)      { v0 = a0.x; v1 = a0.y; }
            else if (slot == 1) { v0 = a0.z; v1 = a0.w; }
            else if (slot == 2) { v0 = a1.x; v1 = a1.y; }
            else                { v0 = a1.z; v1 = a1.w; }
            const float2 bb = *(const float2*)(bias + q * 8 + slot * 2);
            float2 rv;
            rv.x = v0 * 0.25f + bb.x;
            rv.y = v1 * 0.25f + bb.y;
            *(float2*)(out + (size_t)wid * HID + q * 8 + slot * 2) = rv;
        }
    }
}

// ---------------------------------------------------------------------------
// Launch
// ---------------------------------------------------------------------------
extern "C" void kernel_launch(void* const* d_in, const int* in_sizes, int n_in,
                              void* d_out, int out_size, void* d_ws, size_t ws_size,
                              hipStream_t stream) {
    const float* x   = (const float*)d_in[0];
    const int* eidx  = (const int*)d_in[1];
    const float* W1  = (const float*)d_in[2];
    const float* as1 = (const float*)d_in[3];
    const float* ad1 = (const float*)d_in[4];
    const float* b1  = (const float*)d_in[5];
    const float* W2  = (const float*)d_in[6];
    const float* as2 = (const float*)d_in[7];
    const float* ad2 = (const float*)d_in[8];
    const float* b2  = (const float*)d_in[9];
    const float* W3  = (const float*)d_in[10];
    const float* as3 = (const float*)d_in[11];
    const float* ad3 = (const float*)d_in[12];
    const float* b3  = (const float*)d_in[13];

    const int Nn = in_sizes[0] / FEAT;   // 100000
    const int E  = in_sizes[1] / 2;      // 1200000

    char* w = (char*)d_ws;
    size_t off = 0;
    auto alloc = [&](size_t bytes) {
        void* p = w + off;
        off += (bytes + 255) & ~(size_t)255;
        return p;
    };
    _Float16* bufB = (_Float16*)alloc((size_t)Nn * FEAT * 2); // inter-layer fp16
    _Float16* xwh  = (_Float16*)alloc((size_t)Nn * FEAT * 2); // post-GEMM features (fp16)
    float* ssrc   = (float*)alloc((size_t)Nn * HEADS * 4);
    float* sdst   = (float*)alloc((size_t)Nn * HEADS * 4);
    int*   rowptr = (int*)alloc((size_t)(Nn + 1) * 4);
    int*   deg    = (int*)alloc((size_t)Nn * 4);
    int*   rank   = (int*)alloc((size_t)E * 4);
    int*   ssort  = (int*)alloc((size_t)E * 4);
    int*   bsum   = (int*)alloc(64 * 4);
    _Float16* wt  = (_Float16*)alloc((size_t)3 * 2 * WHALF * 2);
    (void)ws_size;

    // ---- CSR build + all-layer W prep
    hipMemsetAsync(deg, 0, (size_t)Nn * 4, stream);
    const int HB = (E + 255) / 256;
    const int PB = (3 * FEAT * WCOLS + 255) / 256;
    hist_prep<<<HB + PB, 256, 0, stream>>>(eidx, deg, rank, E, HB,
                                           W1, W2, W3, as1, ad1, as2, ad2, as3, ad3, wt);
    int nscan = (Nn + SCAN_TILE - 1) / SCAN_TILE;
    scan_partial<<<nscan, SCAN_BLK, 0, stream>>>(deg, bsum, Nn);
    scan_bsum<<<1, 64, 0, stream>>>(bsum, nscan);
    scan_final<<<nscan, SCAN_BLK, 0, stream>>>(deg, bsum, rowptr, Nn);

    const int gemm_grid = (Nn + 255) / 256;     // 391
    const int scat_grid = 784;                  // scatter role blocks (grid-stride)
    const int agg_grid  = (Nn + 3) / 4;

    const float* bs[3] = {b1, b2, b3};

    for (int L = 0; L < 3; L++) {
        const size_t woff = (size_t)L * 2 * WHALF;
        if (L == 0) {
            // fused: gemm L0 (blocks < gemm_grid) + CSR scatter (rest)
            gemm_mfma<0, 1><<<gemm_grid + scat_grid, 512, 0, stream>>>(
                x, (const _Float16*)nullptr, wt + woff,
                xwh, ssrc, sdst, Nn, gemm_grid, eidx, rank, rowptr, ssort, E);
        } else {
            gemm_mfma<1, 0><<<gemm_grid, 512, 0, stream>>>(
                (const float*)nullptr, bufB, wt + woff,
                xwh, ssrc, sdst, Nn, gemm_grid, nullptr, nullptr, nullptr, nullptr, 0);
        }
        edge_agg<<<agg_grid, 256, 0, stream>>>(xwh, ssrc, sdst, rowptr, ssort,
                                               bs[L], (L == 2) ? (float*)d_out : nullptr,
                                               bufB, L == 2, Nn);
    }
}

// Round 11
// 424.807 us; speedup vs baseline: 1.0782x; 1.0206x over previous
//
#include <hip/hip_runtime.h>
#include <math.h>

#define HEADS 4
#define HID 32
#define FEAT 128   // HEADS*HID == IN == hidden width everywhere
#define WCOLS 144  // 128 feature cols + 4 ssrc + 4 sdst + 8 zero-pad = 9 MFMA tiles
#define SLOPE 0.2f
#define WHALF (16 * WCOLS * 8)        // fp16 elements per hi (or lo) W image
#define WH8   (WHALF / 8)             // 2304 half8 per image

typedef __attribute__((ext_vector_type(4))) float frag_cd;  // 4 fp32
typedef __attribute__((ext_vector_type(8))) _Float16 half8; // 16B of fp16
typedef __attribute__((ext_vector_type(2))) _Float16 half2v; // 4B of fp16

// ---------------------------------------------------------------------------
// CSR build. hist's atomicAdd return value IS the edge's rank within its
// destination bucket -> scatter needs no atomic. Self-loops folded into
// edge_agg (no CSR slot). ssorted stores src*256 (byte offset into fp16 xw
// row array). prep_w3 FUSED into the hist launch; scatter FUSED into the
// layer-0 GEMM launch (fills CUs the 391-block gemm grid leaves idle).
// ---------------------------------------------------------------------------

// fused hist (rank capture) + W prep.
// blocks [0, HB): histogram. blocks [HB, HB+PB): augmented-W prep.
__global__ void hist_prep(const int* __restrict__ edge_index, int* __restrict__ deg,
                          int* __restrict__ rank, int E, int HB,
                          const float* __restrict__ W1, const float* __restrict__ W2,
                          const float* __restrict__ W3,
                          const float* __restrict__ as1, const float* __restrict__ ad1,
                          const float* __restrict__ as2, const float* __restrict__ ad2,
                          const float* __restrict__ as3, const float* __restrict__ ad3,
                          _Float16* __restrict__ wt) {
    if ((int)blockIdx.x < HB) {
        int e = blockIdx.x * 256 + threadIdx.x;
        if (e < E) rank[e] = atomicAdd(&deg[edge_index[E + e]], 1);
        return;
    }
    int idx = (blockIdx.x - HB) * 256 + threadIdx.x;
    if (idx >= 3 * FEAT * WCOLS) return;
    int L = idx / (FEAT * WCOLS);
    int rr = idx - L * FEAT * WCOLS;
    int k = rr & 127, c = rr >> 7;           // k in [0,128), c in [0,144)
    const float* W  = (L == 0) ? W1  : (L == 1) ? W2  : W3;
    const float* As = (L == 0) ? as1 : (L == 1) ? as2 : as3;
    const float* Ad = (L == 0) ? ad1 : (L == 1) ? ad2 : ad3;
    float v;
    if (c < 128) {
        v = W[(size_t)k * FEAT + c];
    } else if (c < 136) {
        int s = c - 128;
        int h = s & 3;
        const float* av = (s < 4) ? (As + h * HID) : (Ad + h * HID);
        float acc = 0.f;
        for (int j = 0; j < HID; j++) acc += W[(size_t)k * FEAT + h * HID + j] * av[j];
        v = acc;
    } else {
        v = 0.f;
    }
    _Float16 hi = (_Float16)v;
    _Float16 lo = (_Float16)(v - (float)hi);
    int g = k >> 3, j = k & 7;
    size_t o = (size_t)L * 2 * WHALF + ((size_t)g * WCOLS + c) * 8 + j;
    wt[o] = hi;
    wt[o + WHALF] = lo;
}

#define SCAN_BLK 1024
#define SCAN_CHUNK 4
#define SCAN_TILE (SCAN_BLK * SCAN_CHUNK)

__global__ __launch_bounds__(SCAN_BLK) void scan_partial(const int* __restrict__ deg,
                                                         int* __restrict__ bsum, int Nn) {
    __shared__ int red[SCAN_BLK];
    int t = threadIdx.x;
    int base = blockIdx.x * SCAN_TILE + t * SCAN_CHUNK;
    int s = 0;
#pragma unroll
    for (int i = 0; i < SCAN_CHUNK; i++) {
        int idx = base + i;
        if (idx < Nn) s += deg[idx];
    }
    red[t] = s;
    __syncthreads();
    for (int off = SCAN_BLK / 2; off >= 1; off >>= 1) {
        if (t < off) red[t] += red[t + off];
        __syncthreads();
    }
    if (t == 0) bsum[blockIdx.x] = red[0];
}

__global__ __launch_bounds__(64) void scan_bsum(int* __restrict__ bsum, int nb) {
    int t = threadIdx.x;
    int v = (t < nb) ? bsum[t] : 0;
    int orig = v;
#pragma unroll
    for (int off = 1; off < 64; off <<= 1) {
        int u = __shfl_up(v, off);
        if (t >= off) v += u;
    }
    if (t < nb) bsum[t] = v - orig;
}

__global__ __launch_bounds__(SCAN_BLK) void scan_final(const int* __restrict__ deg,
                                                       const int* __restrict__ bsum,
                                                       int* __restrict__ rowptr, int Nn) {
    __shared__ int sums[SCAN_BLK];
    int t = threadIdx.x;
    int base = blockIdx.x * SCAN_TILE + t * SCAN_CHUNK;
    int loc[SCAN_CHUNK];
    int s = 0;
#pragma unroll
    for (int i = 0; i < SCAN_CHUNK; i++) {
        int idx = base + i;
        int d = (idx < Nn) ? deg[idx] : 0;
        loc[i] = s;
        s += d;
    }
    sums[t] = s;
    __syncthreads();
    for (int off = 1; off < SCAN_BLK; off <<= 1) {
        int v = (t >= off) ? sums[t - off] : 0;
        __syncthreads();
        sums[t] += v;
        __syncthreads();
    }
    int texcl = (t == 0) ? 0 : sums[t - 1];
    int offn = bsum[blockIdx.x] + texcl;
#pragma unroll
    for (int i = 0; i < SCAN_CHUNK; i++) {
        int idx = base + i;
        if (idx < Nn) rowptr[idx] = offn + loc[i];
    }
    if (blockIdx.x == gridDim.x - 1 && t == SCAN_BLK - 1)
        rowptr[Nn] = offn + s;
}

// ---------------------------------------------------------------------------
// GEMM via native fp16 MFMA 16x16x32, augmented hi/lo W staged in LDS via
// global_load_lds (one linear 72KB copy). 512-thread blocks (8 waves,
// 256 rows): 72KB LDS -> 2 blocks/CU = 16 waves/CU. Per-wave shape: 2
// row-tiles, B fragment read once per ct, applied to both. A for all 4
// k-steps prefetched BEFORE the staging barrier. (R8 form -- measured best.)
// Epilogue: fp16 xw store + direct ssrc/sdst store (no shuffles).
// SCAT=1 (layer 0): blocks >= gemm_blocks instead run the no-atomic CSR
// scatter, grid-strided. They fill CUs left idle by the gemm grid.
// ---------------------------------------------------------------------------
template <int A16, int SCAT>
__global__ __launch_bounds__(512) void gemm_mfma(const float* __restrict__ Af,
                                                 const _Float16* __restrict__ Ah,
                                                 const _Float16* __restrict__ wt,
                                                 _Float16* __restrict__ xw,
                                                 float* __restrict__ ssrc,
                                                 float* __restrict__ sdst,
                                                 int nrows, int gemm_blocks,
                                                 const int* __restrict__ eidx,
                                                 const int* __restrict__ rank,
                                                 const int* __restrict__ rowptr,
                                                 int* __restrict__ ssorted, int E) {
    if (SCAT && (int)blockIdx.x >= gemm_blocks) {
        int t = (blockIdx.x - gemm_blocks) * 512 + threadIdx.x;
        int stride = (gridDim.x - gemm_blocks) * 512;
        for (int e = t; e < E; e += stride) {
            int d = eidx[E + e];
            ssorted[rowptr[d] + rank[e]] = eidx[e] << 8;
        }
        return;
    }

    __shared__ _Float16 sW[2 * WHALF];   // 72 KB: hi image then lo image
    int tid = threadIdx.x;
    int wave = tid >> 6, lane = tid & 63;

    // linear staging: 2*WH8 = 4608 half8, 8 waves x 9 iters x 64 lanes
    {
        const half8* g8 = (const half8*)wt;
        half8* s8 = (half8*)sW;
#pragma unroll
        for (int it = 0; it < 9; it++) {
            int base = it * 512 + wave * 64;       // half8 index, wave-uniform
            __builtin_amdgcn_global_load_lds(
                (const __attribute__((address_space(1))) void*)(g8 + base + lane),
                (__attribute__((address_space(3))) void*)(s8 + base), 16, 0, 0);
        }
    }

    int r = lane & 15;     // A-row (load) / D-col (store) index within tile
    int q = lane >> 4;     // k-quad (A/B) / row-quad (D)
    int rowbase = blockIdx.x * 256 + wave * 32;

    int arow0 = rowbase + r;      if (arow0 >= nrows) arow0 = nrows - 1;
    int arow1 = rowbase + 16 + r; if (arow1 >= nrows) arow1 = nrows - 1;

    // A prefetch for all 4 k-steps, issued while the LDS DMA drains
    half8 aP0[4], aP1[4];
    if (A16) {
#pragma unroll
        for (int s = 0; s < 4; s++) {
            int kk = s * 32 + q * 8;
            aP0[s] = *(const half8*)(Ah + (size_t)arow0 * FEAT + kk);
            aP1[s] = *(const half8*)(Ah + (size_t)arow1 * FEAT + kk);
        }
    } else {
#pragma unroll
        for (int s = 0; s < 4; s++) {
            int kk = s * 32 + q * 8;
            const float* p0 = Af + (size_t)arow0 * FEAT + kk;
            const float* p1 = Af + (size_t)arow1 * FEAT + kk;
            float4 x0 = *(const float4*)p0;
            float4 x1 = *(const float4*)(p0 + 4);
            float4 y0 = *(const float4*)p1;
            float4 y1 = *(const float4*)(p1 + 4);
            aP0[s][0] = (_Float16)x0.x; aP0[s][1] = (_Float16)x0.y;
            aP0[s][2] = (_Float16)x0.z; aP0[s][3] = (_Float16)x0.w;
            aP0[s][4] = (_Float16)x1.x; aP0[s][5] = (_Float16)x1.y;
            aP0[s][6] = (_Float16)x1.z; aP0[s][7] = (_Float16)x1.w;
            aP1[s][0] = (_Float16)y0.x; aP1[s][1] = (_Float16)y0.y;
            aP1[s][2] = (_Float16)y0.z; aP1[s][3] = (_Float16)y0.w;
            aP1[s][4] = (_Float16)y1.x; aP1[s][5] = (_Float16)y1.y;
            aP1[s][6] = (_Float16)y1.z; aP1[s][7] = (_Float16)y1.w;
        }
    }
    __syncthreads();

    frag_cd acc0[9], acc1[9];
#pragma unroll
    for (int ct = 0; ct < 9; ct++) {
        acc0[ct] = (frag_cd){0.f, 0.f, 0.f, 0.f};
        acc1[ct] = (frag_cd){0.f, 0.f, 0.f, 0.f};
    }

    const half8* sB = (const half8*)sW;
#pragma unroll
    for (int s = 0; s < 4; s++) {
        int g = s * 4 + q;
        const half8* bh = sB + (size_t)g * WCOLS;
        const half8* bl = sB + WH8 + (size_t)g * WCOLS;
        half8 a0v = aP0[s], a1v = aP1[s];
#pragma unroll
        for (int ct = 0; ct < 9; ct++) {
            int c = ct * 16 + r;
            half8 vh = bh[c];
            half8 vl = bl[c];
            acc0[ct] = __builtin_amdgcn_mfma_f32_16x16x32_f16(a0v, vh, acc0[ct], 0, 0, 0);
            acc0[ct] = __builtin_amdgcn_mfma_f32_16x16x32_f16(a0v, vl, acc0[ct], 0, 0, 0);
            acc1[ct] = __builtin_amdgcn_mfma_f32_16x16x32_f16(a1v, vh, acc1[ct], 0, 0, 0);
            acc1[ct] = __builtin_amdgcn_mfma_f32_16x16x32_f16(a1v, vl, acc1[ct], 0, 0, 0);
        }
    }

    // D layout: col = ct*16 + r, row = q*4 + gi  [m89-verified]
#pragma unroll
    for (int gi = 0; gi < 4; gi++) {
        int rr0 = rowbase + q * 4 + gi;
        if (rr0 < nrows) {
#pragma unroll
            for (int ct = 0; ct < 8; ct++)
                xw[(size_t)rr0 * FEAT + ct * 16 + r] = (_Float16)acc0[ct][gi];
            if (r < 4)      ssrc[rr0 * HEADS + r] = acc0[8][gi];
            else if (r < 8) sdst[rr0 * HEADS + (r - 4)] = acc0[8][gi];
        }
        int rr1 = rowbase + 16 + q * 4 + gi;
        if (rr1 < nrows) {
#pragma unroll
            for (int ct = 0; ct < 8; ct++)
                xw[(size_t)rr1 * FEAT + ct * 16 + r] = (_Float16)acc1[ct][gi];
            if (r < 4)      ssrc[rr1 * HEADS + r] = acc1[8][gi];
            else if (r < 8) sdst[rr1 * HEADS + (r - 4)] = acc1[8][gi];
        }
    }
}

// ---------------------------------------------------------------------------
// Single-pass edge softmax+aggregate, one wave per node, 4 edge slots.
// lane = slot(=lane/16) x q(=lane%16, channel octet 8q..8q+7).
// Per edge: 16 lanes x 16 B (fp16) = full 256 B row. 2-deep PING-PONG
// pipeline: two static stage-sets A (edges +0,+8,+16..) and B (+4,+12,..)
// alternate consume/reload -- zero register-rotation movs (the R8 rotating
// form spent ~8 v_mov/iter; R9's 4-deep ring regressed on prologue
// predication at mean degree 13). Per-slot consumption order unchanged
// (+0,+4,+8,...) -> bit-exact vs R8/R10.
// Self-loop in slot 0 prologue. Epilogue: slot-spread ELU/bias/store.
// ---------------------------------------------------------------------------
__global__ __launch_bounds__(256) void edge_agg(const _Float16* __restrict__ xw,
                                                const float* __restrict__ ssrc,
                                                const float* __restrict__ sdst,
                                                const int* __restrict__ rowptr,
                                                const int* __restrict__ ssorted,
                                                const float* __restrict__ bias,
                                                float* __restrict__ out,
                                                _Float16* __restrict__ outh,
                                                int final_layer, int Nn) {
    int wid = blockIdx.x * 4 + (threadIdx.x >> 6);   // node index
    if (wid >= Nn) return;
    int lane = threadIdx.x & 63;
    int slot = lane >> 4;       // edge slot 0..3
    int q = lane & 15;          // channel octet (channels 8q..8q+7)
    int qh = q >> 2;            // head of this octet

    const char* xwb = (const char*)xw;
    const char* scb = (const char*)ssrc + (qh << 2);  // score base, lane-offset folded
    int xoff = q << 4;          // lane byte offset within row

    int beg = rowptr[wid], end = rowptr[wid + 1];
    float sdh = sdst[wid * HEADS + qh];

    float4 a0 = make_float4(0.f, 0.f, 0.f, 0.f);
    float4 a1 = make_float4(0.f, 0.f, 0.f, 0.f);
    float den = 0.f;

    // self-loop (PyG adds one per node): slot 0 handles it
    if (slot == 0) {
        int off = wid << 8;
        float v = *(const float*)(scb + (off >> 4)) + sdh;
        v = v > 0.f ? v : SLOPE * v;
        float w = __expf(v);
        den = w;
        const half8 hv = *(const half8*)(xwb + (size_t)(unsigned)off + xoff);
        a0.x = w * (float)hv[0]; a0.y = w * (float)hv[1];
        a0.z = w * (float)hv[2]; a0.w = w * (float)hv[3];
        a1.x = w * (float)hv[4]; a1.y = w * (float)hv[5];
        a1.z = w * (float)hv[6]; a1.w = w * (float)hv[7];
    }

    // ping-pong 2-deep pipeline: stage A = edges beg+slot+8k, stage B = +4+8k
    int iA = beg + slot;
    int iB = iA + 4;
    float scA = 0.f, scB = 0.f;
    half8 hvA = (half8)(_Float16)0.f, hvB = (half8)(_Float16)0.f;
    if (iA < end) {
        int off = ssorted[iA];
        scA = *(const float*)(scb + (off >> 4));
        hvA = *(const half8*)(xwb + (size_t)(unsigned)off + xoff);
    }
    if (iB < end) {
        int off = ssorted[iB];
        scB = *(const float*)(scb + (off >> 4));
        hvB = *(const half8*)(xwb + (size_t)(unsigned)off + xoff);
    }
    while (iA < end) {
        // ---- consume stage A, reload it 8 ahead
        {
            float v = scA + sdh;
            v = v > 0.f ? v : SLOPE * v;
            float w = __expf(v);                  // safe: |v| ~ O(6)
            den += w;
            half8 h = hvA;
            int iA8 = iA + 8;
            if (iA8 < end) {
                int off = ssorted[iA8];
                scA = *(const float*)(scb + (off >> 4));
                hvA = *(const half8*)(xwb + (size_t)(unsigned)off + xoff);
            }
            a0.x += w * (float)h[0]; a0.y += w * (float)h[1];
            a0.z += w * (float)h[2]; a0.w += w * (float)h[3];
            a1.x += w * (float)h[4]; a1.y += w * (float)h[5];
            a1.z += w * (float)h[6]; a1.w += w * (float)h[7];
        }
        // ---- consume stage B, reload it 8 ahead
        if (iB < end) {
            float v = scB + sdh;
            v = v > 0.f ? v : SLOPE * v;
            float w = __expf(v);
            den += w;
            half8 h = hvB;
            int iB8 = iB + 8;
            if (iB8 < end) {
                int off = ssorted[iB8];
                scB = *(const float*)(scb + (off >> 4));
                hvB = *(const half8*)(xwb + (size_t)(unsigned)off + xoff);
            }
            a0.x += w * (float)h[0]; a0.y += w * (float)h[1];
            a0.z += w * (float)h[2]; a0.w += w * (float)h[3];
            a1.x += w * (float)h[4]; a1.y += w * (float)h[5];
            a1.z += w * (float)h[6]; a1.w += w * (float)h[7];
        }
        iA += 8;
        iB += 8;
    }

    // fold the 4 edge slots (lane bits 4,5)
#pragma unroll
    for (int m = 16; m <= 32; m <<= 1) {
        a0.x += __shfl_xor(a0.x, m); a0.y += __shfl_xor(a0.y, m);
        a0.z += __shfl_xor(a0.z, m); a0.w += __shfl_xor(a0.w, m);
        a1.x += __shfl_xor(a1.x, m); a1.y += __shfl_xor(a1.y, m);
        a1.z += __shfl_xor(a1.z, m); a1.w += __shfl_xor(a1.w, m);
        den  += __shfl_xor(den, m);
    }

    float inv = 1.f / den;                        // den>0 (self loop); per-head
    a0.x *= inv; a0.y *= inv; a0.z *= inv; a0.w *= inv;
    a1.x *= inv; a1.y *= inv; a1.z *= inv; a1.w *= inv;

    if (!final_layer) {
        // slot-spread epilogue: every slot holds identical folded values;
        // slot s handles channels 8q+2s, 8q+2s+1. All 64 lanes active.
        float v0, v1;
        if (slot == 0)      { v0 = a0.x; v1 = a0.y; }
        else if (slot == 1) { v0 = a0.z; v1 = a0.w; }
        else if (slot == 2) { v0 = a1.x; v1 = a1.y; }
        else                { v0 = a1.z; v1 = a1.w; }
        const float2 bb = *(const float2*)(bias + q * 8 + slot * 2);
        v0 += bb.x; v1 += bb.y;
        // ELU: exp(x)-1 == expm1(x) to ~2^-22 abs here (x<=0, fp32 exp)
        v0 = v0 > 0.f ? v0 : __expf(v0) - 1.f;
        v1 = v1 > 0.f ? v1 : __expf(v1) - 1.f;
        half2v hv2;
        hv2[0] = (_Float16)v0; hv2[1] = (_Float16)v1;
        *(half2v*)(outh + (size_t)wid * FEAT + q * 8 + slot * 2) = hv2;
    } else {
        // head-mean: same within-head channels sit at lanes q, q^4, q^8 (bits 2,3)
#pragma unroll
        for (int m = 4; m <= 8; m <<= 1) {
            a0.x += __shfl_xor(a0.x, m); a0.y += __shfl_xor(a0.y, m);
            a0.z += __shfl_xor(a0.z, m); a0.w += __shfl_xor(a0.w, m);
            a1.x += __shfl_xor(a1.x, m); a1.y += __shfl_xor(a1.y, m);
            a1.z += __shfl_xor(a1.z, m); a1.w += __shfl_xor(a1.w, m);
        }
        if (q < 4) {
            // lanes q<4 hold head-sums for within-head cols 8q..8q+7;
            // slot s handles cols 8q+2s, 8q+2s+1 (16 lanes x 8B = full row)
            float v0, v1;
            if (slot == 0)      { v0 = a0.x; v1 = a0.y; }
            else if (slot == 1) { v0 = a0.z; v1 = a0.w; }
            else if (slot == 2) { v0 = a1.x; v1 = a1.y; }
            else                { v0 = a1.z; v1 = a1.w; }
            const float2 bb = *(const float2*)(bias + q * 8 + slot * 2);
            float2 rv;
            rv.x = v0 * 0.25f + bb.x;
            rv.y = v1 * 0.25f + bb.y;
            *(float2*)(out + (size_t)wid * HID + q * 8 + slot * 2) = rv;
        }
    }
}

// ---------------------------------------------------------------------------
// Launch
// ---------------------------------------------------------------------------
extern "C" void kernel_launch(void* const* d_in, const int* in_sizes, int n_in,
                              void* d_out, int out_size, void* d_ws, size_t ws_size,
                              hipStream_t stream) {
    const float* x   = (const float*)d_in[0];
    const int* eidx  = (const int*)d_in[1];
    const float* W1  = (const float*)d_in[2];
    const float* as1 = (const float*)d_in[3];
    const float* ad1 = (const float*)d_in[4];
    const float* b1  = (const float*)d_in[5];
    const float* W2  = (const float*)d_in[6];
    const float* as2 = (const float*)d_in[7];
    const float* ad2 = (const float*)d_in[8];
    const float* b2  = (const float*)d_in[9];
    const float* W3  = (const float*)d_in[10];
    const float* as3 = (const float*)d_in[11];
    const float* ad3 = (const float*)d_in[12];
    const float* b3  = (const float*)d_in[13];

    const int Nn = in_sizes[0] / FEAT;   // 100000
    const int E  = in_sizes[1] / 2;      // 1200000

    char* w = (char*)d_ws;
    size_t off = 0;
    auto alloc = [&](size_t bytes) {
        void* p = w + off;
        off += (bytes + 255) & ~(size_t)255;
        return p;
    };
    _Float16* bufB = (_Float16*)alloc((size_t)Nn * FEAT * 2); // inter-layer fp16
    _Float16* xwh  = (_Float16*)alloc((size_t)Nn * FEAT * 2); // post-GEMM features (fp16)
    float* ssrc   = (float*)alloc((size_t)Nn * HEADS * 4);
    float* sdst   = (float*)alloc((size_t)Nn * HEADS * 4);
    int*   rowptr = (int*)alloc((size_t)(Nn + 1) * 4);
    int*   deg    = (int*)alloc((size_t)Nn * 4);
    int*   rank   = (int*)alloc((size_t)E * 4);
    int*   ssort  = (int*)alloc((size_t)E * 4);
    int*   bsum   = (int*)alloc(64 * 4);
    _Float16* wt  = (_Float16*)alloc((size_t)3 * 2 * WHALF * 2);
    (void)ws_size;

    // ---- CSR build + all-layer W prep
    hipMemsetAsync(deg, 0, (size_t)Nn * 4, stream);
    const int HB = (E + 255) / 256;
    const int PB = (3 * FEAT * WCOLS + 255) / 256;
    hist_prep<<<HB + PB, 256, 0, stream>>>(eidx, deg, rank, E, HB,
                                           W1, W2, W3, as1, ad1, as2, ad2, as3, ad3, wt);
    int nscan = (Nn + SCAN_TILE - 1) / SCAN_TILE;
    scan_partial<<<nscan, SCAN_BLK, 0, stream>>>(deg, bsum, Nn);
    scan_bsum<<<1, 64, 0, stream>>>(bsum, nscan);
    scan_final<<<nscan, SCAN_BLK, 0, stream>>>(deg, bsum, rowptr, Nn);

    const int gemm_grid = (Nn + 255) / 256;     // 391
    const int scat_grid = 784;                  // scatter role blocks (grid-stride)
    const int agg_grid  = (Nn + 3) / 4;

    const float* bs[3] = {b1, b2, b3};

    for (int L = 0; L < 3; L++) {
        const size_t woff = (size_t)L * 2 * WHALF;
        if (L == 0) {
            // fused: gemm L0 (blocks < gemm_grid) + CSR scatter (rest)
            gemm_mfma<0, 1><<<gemm_grid + scat_grid, 512, 0, stream>>>(
                x, (const _Float16*)nullptr, wt + woff,
                xwh, ssrc, sdst, Nn, gemm_grid, eidx, rank, rowptr, ssort, E);
        } else {
            gemm_mfma<1, 0><<<gemm_grid, 512, 0, stream>>>(
                (const float*)nullptr, bufB, wt + woff,
                xwh, ssrc, sdst, Nn, gemm_grid, nullptr, nullptr, nullptr, nullptr, 0);
        }
        edge_agg<<<agg_grid, 256, 0, stream>>>(xwh, ssrc, sdst, rowptr, ssort,
                                               bs[L], (L == 2) ? (float*)d_out : nullptr,
                                               bufB, L == 2, Nn);
    }
}

// Round 12
// 414.129 us; speedup vs baseline: 1.1060x; 1.0258x over previous
//
#include <hip/hip_runtime.h>
#include <math.h>

#define HEADS 4
#define HID 32
#define FEAT 128   // HEADS*HID == IN == hidden width everywhere
#define WCOLS 144  // 128 feature cols + 4 ssrc + 4 sdst + 8 zero-pad = 9 MFMA tiles
#define SLOPE 0.2f
#define WHALF (16 * WCOLS * 8)        // fp16 elements per hi (or lo) W image
#define WH8   (WHALF / 8)             // 2304 half8 per image

typedef __attribute__((ext_vector_type(4))) float frag_cd;  // 4 fp32
typedef __attribute__((ext_vector_type(8))) _Float16 half8; // 16B of fp16
typedef __attribute__((ext_vector_type(4))) _Float16 half4v; // 8B of fp16

// ---------------------------------------------------------------------------
// CSR build. hist's atomicAdd return value IS the edge's rank within its
// destination bucket -> scatter needs no atomic. Self-loops folded into
// edge_agg (no CSR slot). ssorted stores src*256 (byte offset into fp16 xw
// row array). prep_w3 FUSED into the hist launch; scatter FUSED into the
// layer-0 GEMM launch (fills CUs the 391-block gemm grid leaves idle).
// ---------------------------------------------------------------------------

// fused hist (rank capture) + W prep.
// blocks [0, HB): histogram. blocks [HB, HB+PB): augmented-W prep.
__global__ void hist_prep(const int* __restrict__ edge_index, int* __restrict__ deg,
                          int* __restrict__ rank, int E, int HB,
                          const float* __restrict__ W1, const float* __restrict__ W2,
                          const float* __restrict__ W3,
                          const float* __restrict__ as1, const float* __restrict__ ad1,
                          const float* __restrict__ as2, const float* __restrict__ ad2,
                          const float* __restrict__ as3, const float* __restrict__ ad3,
                          _Float16* __restrict__ wt) {
    if ((int)blockIdx.x < HB) {
        int e = blockIdx.x * 256 + threadIdx.x;
        if (e < E) rank[e] = atomicAdd(&deg[edge_index[E + e]], 1);
        return;
    }
    int idx = (blockIdx.x - HB) * 256 + threadIdx.x;
    if (idx >= 3 * FEAT * WCOLS) return;
    int L = idx / (FEAT * WCOLS);
    int rr = idx - L * FEAT * WCOLS;
    int k = rr & 127, c = rr >> 7;           // k in [0,128), c in [0,144)
    const float* W  = (L == 0) ? W1  : (L == 1) ? W2  : W3;
    const float* As = (L == 0) ? as1 : (L == 1) ? as2 : as3;
    const float* Ad = (L == 0) ? ad1 : (L == 1) ? ad2 : ad3;
    float v;
    if (c < 128) {
        v = W[(size_t)k * FEAT + c];
    } else if (c < 136) {
        int s = c - 128;
        int h = s & 3;
        const float* av = (s < 4) ? (As + h * HID) : (Ad + h * HID);
        float acc = 0.f;
        for (int j = 0; j < HID; j++) acc += W[(size_t)k * FEAT + h * HID + j] * av[j];
        v = acc;
    } else {
        v = 0.f;
    }
    _Float16 hi = (_Float16)v;
    _Float16 lo = (_Float16)(v - (float)hi);
    int g = k >> 3, j = k & 7;
    size_t o = (size_t)L * 2 * WHALF + ((size_t)g * WCOLS + c) * 8 + j;
    wt[o] = hi;
    wt[o + WHALF] = lo;
}

#define SCAN_BLK 1024
#define SCAN_CHUNK 4
#define SCAN_TILE (SCAN_BLK * SCAN_CHUNK)

__global__ __launch_bounds__(SCAN_BLK) void scan_partial(const int* __restrict__ deg,
                                                         int* __restrict__ bsum, int Nn) {
    __shared__ int red[SCAN_BLK];
    int t = threadIdx.x;
    int base = blockIdx.x * SCAN_TILE + t * SCAN_CHUNK;
    int s = 0;
#pragma unroll
    for (int i = 0; i < SCAN_CHUNK; i++) {
        int idx = base + i;
        if (idx < Nn) s += deg[idx];
    }
    red[t] = s;
    __syncthreads();
    for (int off = SCAN_BLK / 2; off >= 1; off >>= 1) {
        if (t < off) red[t] += red[t + off];
        __syncthreads();
    }
    if (t == 0) bsum[blockIdx.x] = red[0];
}

__global__ __launch_bounds__(64) void scan_bsum(int* __restrict__ bsum, int nb) {
    int t = threadIdx.x;
    int v = (t < nb) ? bsum[t] : 0;
    int orig = v;
#pragma unroll
    for (int off = 1; off < 64; off <<= 1) {
        int u = __shfl_up(v, off);
        if (t >= off) v += u;
    }
    if (t < nb) bsum[t] = v - orig;
}

__global__ __launch_bounds__(SCAN_BLK) void scan_final(const int* __restrict__ deg,
                                                       const int* __restrict__ bsum,
                                                       int* __restrict__ rowptr, int Nn) {
    __shared__ int sums[SCAN_BLK];
    int t = threadIdx.x;
    int base = blockIdx.x * SCAN_TILE + t * SCAN_CHUNK;
    int loc[SCAN_CHUNK];
    int s = 0;
#pragma unroll
    for (int i = 0; i < SCAN_CHUNK; i++) {
        int idx = base + i;
        int d = (idx < Nn) ? deg[idx] : 0;
        loc[i] = s;
        s += d;
    }
    sums[t] = s;
    __syncthreads();
    for (int off = 1; off < SCAN_BLK; off <<= 1) {
        int v = (t >= off) ? sums[t - off] : 0;
        __syncthreads();
        sums[t] += v;
        __syncthreads();
    }
    int texcl = (t == 0) ? 0 : sums[t - 1];
    int offn = bsum[blockIdx.x] + texcl;
#pragma unroll
    for (int i = 0; i < SCAN_CHUNK; i++) {
        int idx = base + i;
        if (idx < Nn) rowptr[idx] = offn + loc[i];
    }
    if (blockIdx.x == gridDim.x - 1 && t == SCAN_BLK - 1)
        rowptr[Nn] = offn + s;
}

// ---------------------------------------------------------------------------
// GEMM via native fp16 MFMA 16x16x32, augmented hi/lo W staged in LDS via
// global_load_lds (one linear 72KB copy). 512-thread blocks (8 waves,
// 256 rows): 72KB LDS -> 2 blocks/CU = 16 waves/CU. Per-wave shape: 2
// row-tiles, B fragment read once per ct, applied to both. A for all 4
// k-steps prefetched BEFORE the staging barrier. (R8 form -- measured best.)
// Epilogue: fp16 xw store + direct ssrc/sdst store (no shuffles).
// SCAT=1 (layer 0): blocks >= gemm_blocks instead run the no-atomic CSR
// scatter, grid-strided. They fill CUs left idle by the gemm grid.
// ---------------------------------------------------------------------------
template <int A16, int SCAT>
__global__ __launch_bounds__(512) void gemm_mfma(const float* __restrict__ Af,
                                                 const _Float16* __restrict__ Ah,
                                                 const _Float16* __restrict__ wt,
                                                 _Float16* __restrict__ xw,
                                                 float* __restrict__ ssrc,
                                                 float* __restrict__ sdst,
                                                 int nrows, int gemm_blocks,
                                                 const int* __restrict__ eidx,
                                                 const int* __restrict__ rank,
                                                 const int* __restrict__ rowptr,
                                                 int* __restrict__ ssorted, int E) {
    if (SCAT && (int)blockIdx.x >= gemm_blocks) {
        int t = (blockIdx.x - gemm_blocks) * 512 + threadIdx.x;
        int stride = (gridDim.x - gemm_blocks) * 512;
        for (int e = t; e < E; e += stride) {
            int d = eidx[E + e];
            ssorted[rowptr[d] + rank[e]] = eidx[e] << 8;
        }
        return;
    }

    __shared__ _Float16 sW[2 * WHALF];   // 72 KB: hi image then lo image
    int tid = threadIdx.x;
    int wave = tid >> 6, lane = tid & 63;

    // linear staging: 2*WH8 = 4608 half8, 8 waves x 9 iters x 64 lanes
    {
        const half8* g8 = (const half8*)wt;
        half8* s8 = (half8*)sW;
#pragma unroll
        for (int it = 0; it < 9; it++) {
            int base = it * 512 + wave * 64;       // half8 index, wave-uniform
            __builtin_amdgcn_global_load_lds(
                (const __attribute__((address_space(1))) void*)(g8 + base + lane),
                (__attribute__((address_space(3))) void*)(s8 + base), 16, 0, 0);
        }
    }

    int r = lane & 15;     // A-row (load) / D-col (store) index within tile
    int q = lane >> 4;     // k-quad (A/B) / row-quad (D)
    int rowbase = blockIdx.x * 256 + wave * 32;

    int arow0 = rowbase + r;      if (arow0 >= nrows) arow0 = nrows - 1;
    int arow1 = rowbase + 16 + r; if (arow1 >= nrows) arow1 = nrows - 1;

    // A prefetch for all 4 k-steps, issued while the LDS DMA drains
    half8 aP0[4], aP1[4];
    if (A16) {
#pragma unroll
        for (int s = 0; s < 4; s++) {
            int kk = s * 32 + q * 8;
            aP0[s] = *(const half8*)(Ah + (size_t)arow0 * FEAT + kk);
            aP1[s] = *(const half8*)(Ah + (size_t)arow1 * FEAT + kk);
        }
    } else {
#pragma unroll
        for (int s = 0; s < 4; s++) {
            int kk = s * 32 + q * 8;
            const float* p0 = Af + (size_t)arow0 * FEAT + kk;
            const float* p1 = Af + (size_t)arow1 * FEAT + kk;
            float4 x0 = *(const float4*)p0;
            float4 x1 = *(const float4*)(p0 + 4);
            float4 y0 = *(const float4*)p1;
            float4 y1 = *(const float4*)(p1 + 4);
            aP0[s][0] = (_Float16)x0.x; aP0[s][1] = (_Float16)x0.y;
            aP0[s][2] = (_Float16)x0.z; aP0[s][3] = (_Float16)x0.w;
            aP0[s][4] = (_Float16)x1.x; aP0[s][5] = (_Float16)x1.y;
            aP0[s][6] = (_Float16)x1.z; aP0[s][7] = (_Float16)x1.w;
            aP1[s][0] = (_Float16)y0.x; aP1[s][1] = (_Float16)y0.y;
            aP1[s][2] = (_Float16)y0.z; aP1[s][3] = (_Float16)y0.w;
            aP1[s][4] = (_Float16)y1.x; aP1[s][5] = (_Float16)y1.y;
            aP1[s][6] = (_Float16)y1.z; aP1[s][7] = (_Float16)y1.w;
        }
    }
    __syncthreads();

    frag_cd acc0[9], acc1[9];
#pragma unroll
    for (int ct = 0; ct < 9; ct++) {
        acc0[ct] = (frag_cd){0.f, 0.f, 0.f, 0.f};
        acc1[ct] = (frag_cd){0.f, 0.f, 0.f, 0.f};
    }

    const half8* sB = (const half8*)sW;
#pragma unroll
    for (int s = 0; s < 4; s++) {
        int g = s * 4 + q;
        const half8* bh = sB + (size_t)g * WCOLS;
        const half8* bl = sB + WH8 + (size_t)g * WCOLS;
        half8 a0v = aP0[s], a1v = aP1[s];
#pragma unroll
        for (int ct = 0; ct < 9; ct++) {
            int c = ct * 16 + r;
            half8 vh = bh[c];
            half8 vl = bl[c];
            acc0[ct] = __builtin_amdgcn_mfma_f32_16x16x32_f16(a0v, vh, acc0[ct], 0, 0, 0);
            acc0[ct] = __builtin_amdgcn_mfma_f32_16x16x32_f16(a0v, vl, acc0[ct], 0, 0, 0);
            acc1[ct] = __builtin_amdgcn_mfma_f32_16x16x32_f16(a1v, vh, acc1[ct], 0, 0, 0);
            acc1[ct] = __builtin_amdgcn_mfma_f32_16x16x32_f16(a1v, vl, acc1[ct], 0, 0, 0);
        }
    }

    // D layout: col = ct*16 + r, row = q*4 + gi  [m89-verified]
#pragma unroll
    for (int gi = 0; gi < 4; gi++) {
        int rr0 = rowbase + q * 4 + gi;
        if (rr0 < nrows) {
#pragma unroll
            for (int ct = 0; ct < 8; ct++)
                xw[(size_t)rr0 * FEAT + ct * 16 + r] = (_Float16)acc0[ct][gi];
            if (r < 4)      ssrc[rr0 * HEADS + r] = acc0[8][gi];
            else if (r < 8) sdst[rr0 * HEADS + (r - 4)] = acc0[8][gi];
        }
        int rr1 = rowbase + 16 + q * 4 + gi;
        if (rr1 < nrows) {
#pragma unroll
            for (int ct = 0; ct < 8; ct++)
                xw[(size_t)rr1 * FEAT + ct * 16 + r] = (_Float16)acc1[ct][gi];
            if (r < 4)      ssrc[rr1 * HEADS + r] = acc1[8][gi];
            else if (r < 8) sdst[rr1 * HEADS + (r - 4)] = acc1[8][gi];
        }
    }
}

// ---------------------------------------------------------------------------
// Single-pass edge softmax+aggregate, TWO nodes per wave: lanes [0,32) serve
// node A, lanes [32,64) node B. Per node: 2 edge slots x 16 lanes x 16B
// (full 256B row), 2-deep ping-pong -> 8 gathers in flight per wave (same
// MLP as the 1-node/4-slot form). Why: per-node fixed cost (setup ~35 inst,
// self-loop ~15, fold, epilogue) was ~100 inst vs ~85 loop inst; sharing a
// wave between 2 nodes halves the setup/self-loop per node and cuts the
// slot fold from 2 shfl levels to 1 (xor 16, stays within each half).
// Per-slot stride is 2 (was 4): fp32 accumulation reordered, tiny drift ok.
// Epilogue: slot-spread, 4 channels per lane (half4/float4, coalesced).
// ---------------------------------------------------------------------------
__global__ __launch_bounds__(256) void edge_agg(const _Float16* __restrict__ xw,
                                                const float* __restrict__ ssrc,
                                                const float* __restrict__ sdst,
                                                const int* __restrict__ rowptr,
                                                const int* __restrict__ ssorted,
                                                const float* __restrict__ bias,
                                                float* __restrict__ out,
                                                _Float16* __restrict__ outh,
                                                int final_layer, int Nn) {
    int tid = threadIdx.x;
    int lane = tid & 63;
    int half = lane >> 5;                            // node sub-index in wave
    int wid = blockIdx.x * 8 + ((tid >> 6) << 1) + half;
    if (wid >= Nn) return;                           // whole 32-lane half exits
    int l32 = lane & 31;
    int slot = l32 >> 4;        // edge slot 0..1 (per node)
    int q = l32 & 15;           // channel octet (channels 8q..8q+7)
    int qh = q >> 2;            // head of this octet

    const char* xwb = (const char*)xw;
    const char* scb = (const char*)ssrc + (qh << 2); // score base, lane-offset folded
    int xoff = q << 4;          // lane byte offset within row

    int beg = rowptr[wid], end = rowptr[wid + 1];
    float sdh = sdst[wid * HEADS + qh];

    float4 a0 = make_float4(0.f, 0.f, 0.f, 0.f);
    float4 a1 = make_float4(0.f, 0.f, 0.f, 0.f);
    float den = 0.f;

    // self-loop (PyG adds one per node): slot 0 (16 lanes/node = full row)
    if (slot == 0) {
        int off = wid << 8;
        float v = *(const float*)(scb + (off >> 4)) + sdh;
        v = v > 0.f ? v : SLOPE * v;
        float w = __expf(v);
        den = w;
        const half8 hv = *(const half8*)(xwb + (size_t)(unsigned)off + xoff);
        a0.x = w * (float)hv[0]; a0.y = w * (float)hv[1];
        a0.z = w * (float)hv[2]; a0.w = w * (float)hv[3];
        a1.x = w * (float)hv[4]; a1.y = w * (float)hv[5];
        a1.z = w * (float)hv[6]; a1.w = w * (float)hv[7];
    }

    // ping-pong 2-deep pipeline: stage A = edges beg+slot+4k, stage B = +2+4k
    // (per-slot stride 2; 2 slots cover all edges)
    int iA = beg + slot;
    int iB = iA + 2;
    float scA = 0.f, scB = 0.f;
    half8 hvA = (half8)(_Float16)0.f, hvB = (half8)(_Float16)0.f;
    if (iA < end) {
        int off = ssorted[iA];
        scA = *(const float*)(scb + (off >> 4));
        hvA = *(const half8*)(xwb + (size_t)(unsigned)off + xoff);
    }
    if (iB < end) {
        int off = ssorted[iB];
        scB = *(const float*)(scb + (off >> 4));
        hvB = *(const half8*)(xwb + (size_t)(unsigned)off + xoff);
    }
    while (iA < end) {
        // ---- consume stage A, reload it 4 ahead
        {
            float v = scA + sdh;
            v = v > 0.f ? v : SLOPE * v;
            float w = __expf(v);                  // safe: |v| ~ O(6)
            den += w;
            half8 h = hvA;
            int iA4 = iA + 4;
            if (iA4 < end) {
                int off = ssorted[iA4];
                scA = *(const float*)(scb + (off >> 4));
                hvA = *(const half8*)(xwb + (size_t)(unsigned)off + xoff);
            }
            a0.x += w * (float)h[0]; a0.y += w * (float)h[1];
            a0.z += w * (float)h[2]; a0.w += w * (float)h[3];
            a1.x += w * (float)h[4]; a1.y += w * (float)h[5];
            a1.z += w * (float)h[6]; a1.w += w * (float)h[7];
        }
        // ---- consume stage B, reload it 4 ahead
        if (iB < end) {
            float v = scB + sdh;
            v = v > 0.f ? v : SLOPE * v;
            float w = __expf(v);
            den += w;
            half8 h = hvB;
            int iB4 = iB + 4;
            if (iB4 < end) {
                int off = ssorted[iB4];
                scB = *(const float*)(scb + (off >> 4));
                hvB = *(const half8*)(xwb + (size_t)(unsigned)off + xoff);
            }
            a0.x += w * (float)h[0]; a0.y += w * (float)h[1];
            a0.z += w * (float)h[2]; a0.w += w * (float)h[3];
            a1.x += w * (float)h[4]; a1.y += w * (float)h[5];
            a1.z += w * (float)h[6]; a1.w += w * (float)h[7];
        }
        iA += 4;
        iB += 4;
    }

    // fold the 2 edge slots (lane bit 4 -- stays within each 32-lane half)
    a0.x += __shfl_xor(a0.x, 16); a0.y += __shfl_xor(a0.y, 16);
    a0.z += __shfl_xor(a0.z, 16); a0.w += __shfl_xor(a0.w, 16);
    a1.x += __shfl_xor(a1.x, 16); a1.y += __shfl_xor(a1.y, 16);
    a1.z += __shfl_xor(a1.z, 16); a1.w += __shfl_xor(a1.w, 16);
    den  += __shfl_xor(den, 16);

    float inv = 1.f / den;                        // den>0 (self loop); per-head
    a0.x *= inv; a0.y *= inv; a0.z *= inv; a0.w *= inv;
    a1.x *= inv; a1.y *= inv; a1.z *= inv; a1.w *= inv;

    if (!final_layer) {
        // slot-spread epilogue: both slots hold identical folded values;
        // slot 0 stores channels 8q..8q+3 (a0), slot 1 stores 8q+4..8q+7 (a1).
        float4 vv = (slot == 0) ? a0 : a1;
        const float4 bb = *(const float4*)(bias + q * 8 + slot * 4);
        vv.x += bb.x; vv.y += bb.y; vv.z += bb.z; vv.w += bb.w;
        // ELU: exp(x)-1 == expm1(x) to ~2^-22 abs here (x<=0, fp32 exp)
        vv.x = vv.x > 0.f ? vv.x : __expf(vv.x) - 1.f;
        vv.y = vv.y > 0.f ? vv.y : __expf(vv.y) - 1.f;
        vv.z = vv.z > 0.f ? vv.z : __expf(vv.z) - 1.f;
        vv.w = vv.w > 0.f ? vv.w : __expf(vv.w) - 1.f;
        half4v hv4;
        hv4[0] = (_Float16)vv.x; hv4[1] = (_Float16)vv.y;
        hv4[2] = (_Float16)vv.z; hv4[3] = (_Float16)vv.w;
        *(half4v*)(outh + (size_t)wid * FEAT + q * 8 + slot * 4) = hv4;
    } else {
        // head-mean: same within-head channels sit at lanes q, q^4, q^8
        // (bits 2,3 of lane -- within each half and slot)
#pragma unroll
        for (int m = 4; m <= 8; m <<= 1) {
            a0.x += __shfl_xor(a0.x, m); a0.y += __shfl_xor(a0.y, m);
            a0.z += __shfl_xor(a0.z, m); a0.w += __shfl_xor(a0.w, m);
            a1.x += __shfl_xor(a1.x, m); a1.y += __shfl_xor(a1.y, m);
            a1.z += __shfl_xor(a1.z, m); a1.w += __shfl_xor(a1.w, m);
        }
        if (q < 4) {
            // lanes q<4 hold head-sums for within-head cols 8q..8q+7;
            // slot s stores cols 8q+4s..8q+4s+3 (8 lanes x 16B = full row)
            float4 vv = (slot == 0) ? a0 : a1;
            const float4 bb = *(const float4*)(bias + q * 8 + slot * 4);
            float4 rv;
            rv.x = vv.x * 0.25f + bb.x;
            rv.y = vv.y * 0.25f + bb.y;
            rv.z = vv.z * 0.25f + bb.z;
            rv.w = vv.w * 0.25f + bb.w;
            *(float4*)(out + (size_t)wid * HID + q * 8 + slot * 4) = rv;
        }
    }
}

// ---------------------------------------------------------------------------
// Launch
// ---------------------------------------------------------------------------
extern "C" void kernel_launch(void* const* d_in, const int* in_sizes, int n_in,
                              void* d_out, int out_size, void* d_ws, size_t ws_size,
                              hipStream_t stream) {
    const float* x   = (const float*)d_in[0];
    const int* eidx  = (const int*)d_in[1];
    const float* W1  = (const float*)d_in[2];
    const float* as1 = (const float*)d_in[3];
    const float* ad1 = (const float*)d_in[4];
    const float* b1  = (const float*)d_in[5];
    const float* W2  = (const float*)d_in[6];
    const float* as2 = (const float*)d_in[7];
    const float* ad2 = (const float*)d_in[8];
    const float* b2  = (const float*)d_in[9];
    const float* W3  = (const float*)d_in[10];
    const float* as3 = (const float*)d_in[11];
    const float* ad3 = (const float*)d_in[12];
    const float* b3  = (const float*)d_in[13];

    const int Nn = in_sizes[0] / FEAT;   // 100000
    const int E  = in_sizes[1] / 2;      // 1200000

    char* w = (char*)d_ws;
    size_t off = 0;
    auto alloc = [&](size_t bytes) {
        void* p = w + off;
        off += (bytes + 255) & ~(size_t)255;
        return p;
    };
    _Float16* bufB = (_Float16*)alloc((size_t)Nn * FEAT * 2); // inter-layer fp16
    _Float16* xwh  = (_Float16*)alloc((size_t)Nn * FEAT * 2); // post-GEMM features (fp16)
    float* ssrc   = (float*)alloc((size_t)Nn * HEADS * 4);
    float* sdst   = (float*)alloc((size_t)Nn * HEADS * 4);
    int*   rowptr = (int*)alloc((size_t)(Nn + 1) * 4);
    int*   deg    = (int*)alloc((size_t)Nn * 4);
    int*   rank   = (int*)alloc((size_t)E * 4);
    int*   ssort  = (int*)alloc((size_t)E * 4);
    int*   bsum   = (int*)alloc(64 * 4);
    _Float16* wt  = (_Float16*)alloc((size_t)3 * 2 * WHALF * 2);
    (void)ws_size;

    // ---- CSR build + all-layer W prep
    hipMemsetAsync(deg, 0, (size_t)Nn * 4, stream);
    const int HB = (E + 255) / 256;
    const int PB = (3 * FEAT * WCOLS + 255) / 256;
    hist_prep<<<HB + PB, 256, 0, stream>>>(eidx, deg, rank, E, HB,
                                           W1, W2, W3, as1, ad1, as2, ad2, as3, ad3, wt);
    int nscan = (Nn + SCAN_TILE - 1) / SCAN_TILE;
    scan_partial<<<nscan, SCAN_BLK, 0, stream>>>(deg, bsum, Nn);
    scan_bsum<<<1, 64, 0, stream>>>(bsum, nscan);
    scan_final<<<nscan, SCAN_BLK, 0, stream>>>(deg, bsum, rowptr, Nn);

    const int gemm_grid = (Nn + 255) / 256;     // 391
    const int scat_grid = 784;                  // scatter role blocks (grid-stride)
    const int agg_grid  = (Nn + 7) / 8;

    const float* bs[3] = {b1, b2, b3};

    for (int L = 0; L < 3; L++) {
        const size_t woff = (size_t)L * 2 * WHALF;
        if (L == 0) {
            // fused: gemm L0 (blocks < gemm_grid) + CSR scatter (rest)
            gemm_mfma<0, 1><<<gemm_grid + scat_grid, 512, 0, stream>>>(
                x, (const _Float16*)nullptr, wt + woff,
                xwh, ssrc, sdst, Nn, gemm_grid, eidx, rank, rowptr, ssort, E);
        } else {
            gemm_mfma<1, 0><<<gemm_grid, 512, 0, stream>>>(
                (const float*)nullptr, bufB, wt + woff,
                xwh, ssrc, sdst, Nn, gemm_grid, nullptr, nullptr, nullptr, nullptr, 0);
        }
        edge_agg<<<agg_grid, 256, 0, stream>>>(xwh, ssrc, sdst, rowptr, ssort,
                                               bs[L], (L == 2) ? (float*)d_out : nullptr,
                                               bufB, L == 2, Nn);
    }
}